// Round 4
// baseline (578.652 us; speedup 1.0000x reference)
//
#include <hip/hip_runtime.h>
#include <hip/hip_bf16.h>

// Problem constants (verified against setup_inputs)
#define C_DIN 128
#define C_H 4
#define C_CH 64     // per-head channels (CHID == COUT == 64)
#define C_HC 256    // H * CH
#define C_S 32

__device__ __forceinline__ float lrelu(float x) { return x >= 0.f ? x : 0.2f * x; }

__device__ __forceinline__ float wave_sum(float v) {
#pragma unroll
    for (int off = 32; off > 0; off >>= 1) v += __shfl_xor(v, off);
    return v;
}
__device__ __forceinline__ float wave_max(float v) {
#pragma unroll
    for (int off = 32; off > 0; off >>= 1) v = fmaxf(v, __shfl_xor(v, off));
    return v;
}

// ---------------- CSR build ----------------
__global__ void k_count(const int* __restrict__ dst, int* __restrict__ deg, int E) {
    int e = blockIdx.x * blockDim.x + threadIdx.x;
    if (e < E) atomicAdd(&deg[dst[e]], 1);
}

// single block of 1024 threads: exclusive scan of deg[0..n) -> row_ptr[0..n], cursor copy
__global__ void k_scan(const int* __restrict__ deg, int* __restrict__ row_ptr,
                       int* __restrict__ cursor, int n) {
    __shared__ int part[1024];
    int t = threadIdx.x;
    const int C = (n + 1023) / 1024;
    int base = t * C;
    int s = 0;
    for (int k = 0; k < C; ++k) {
        int idx = base + k;
        if (idx < n) s += deg[idx];
    }
    part[t] = s;
    __syncthreads();
    for (int off = 1; off < 1024; off <<= 1) {
        int v = (t >= off) ? part[t - off] : 0;
        __syncthreads();
        part[t] += v;
        __syncthreads();
    }
    int run = (t == 0) ? 0 : part[t - 1];
    for (int k = 0; k < C; ++k) {
        int idx = base + k;
        if (idx < n) { row_ptr[idx] = run; cursor[idx] = run; run += deg[idx]; }
    }
    if (t == 1023) row_ptr[n] = run;
}

__global__ void k_scatter(const int* __restrict__ src, const int* __restrict__ dst,
                          int* __restrict__ cursor, int* __restrict__ adj_src,
                          int* __restrict__ adj_eid, int E) {
    int e = blockIdx.x * blockDim.x + threadIdx.x;
    if (e < E) {
        int d = dst[e];
        int p = atomicAdd(&cursor[d], 1);
        adj_src[p] = src[e];
        adj_eid[p] = e;
    }
}

// ---------------- layer 1 GEMM: h = x @ W1^T, fused a_s1/a_d1 ----------------
#define GROWS 16
__global__ void k_gemm1(const float* __restrict__ x, const float* __restrict__ W1,
                        const float* __restrict__ att_s, const float* __restrict__ att_d,
                        float* __restrict__ h, float* __restrict__ a_s, float* __restrict__ a_d,
                        int n) {
    __shared__ float4 xs[GROWS * 32];  // 16 rows x 128 cols
    int r0 = blockIdx.x * GROWS;
    int t = threadIdx.x;
    const float4* x4 = (const float4*)x;
    for (int idx = t; idx < GROWS * 32; idx += 256) {
        int r = idx >> 5, k4 = idx & 31;
        int rr = r0 + r;
        xs[idx] = (rr < n) ? x4[(size_t)rr * 32 + k4] : make_float4(0, 0, 0, 0);
    }
    __syncthreads();
    int c = t;  // output column 0..255
    const float4* w4 = (const float4*)(W1 + (size_t)c * C_DIN);
    float acc[GROWS];
#pragma unroll
    for (int r = 0; r < GROWS; ++r) acc[r] = 0.f;
    for (int k4 = 0; k4 < 32; ++k4) {
        float4 w = w4[k4];
#pragma unroll
        for (int r = 0; r < GROWS; ++r) {
            float4 xv = xs[r * 32 + k4];
            acc[r] += xv.x * w.x + xv.y * w.y + xv.z * w.z + xv.w * w.w;
        }
    }
    float asc = att_s[c], adc = att_d[c];
    int hh = t >> 6, lane = t & 63;
#pragma unroll
    for (int r = 0; r < GROWS; ++r) {
        int rr = r0 + r;
        if (rr < n) h[(size_t)rr * C_HC + c] = acc[r];
        float vs = acc[r] * asc, vd = acc[r] * adc;
#pragma unroll
        for (int off = 32; off > 0; off >>= 1) {
            vs += __shfl_xor(vs, off);
            vd += __shfl_xor(vd, off);
        }
        if (lane == 0 && rr < n) { a_s[rr * C_H + hh] = vs; a_d[rr * C_H + hh] = vd; }
    }
}

// ---------------- layer 1 per-dst softmax + aggregate (+self loop) -> h1 ----------------
__global__ void k_layer1(const int* __restrict__ row_ptr, const int* __restrict__ adj_src,
                         const float* __restrict__ h, const float* __restrict__ a_s,
                         const float* __restrict__ a_d, const float* __restrict__ bias1,
                         float* __restrict__ h1) {
    int d = blockIdx.x;
    int t = threadIdx.x, hh = t >> 6, lane = t & 63;
    int beg = row_ptr[d], end = row_ptr[d + 1];
    float adh = a_d[d * C_H + hh];
    float selflogit = lrelu(a_s[d * C_H + hh] + adh);
    // phase A: max (self included)
    float m = selflogit;
    for (int e = beg + lane; e < end; e += 64) {
        int s = adj_src[e];
        m = fmaxf(m, lrelu(a_s[s * C_H + hh] + adh));
    }
    m = wave_max(m);
    // phase B: sum of exp (self once)
    float sum = (lane == 0) ? expf(selflogit - m) : 0.f;
    for (int e = beg + lane; e < end; e += 64) {
        int s = adj_src[e];
        sum += expf(lrelu(a_s[s * C_H + hh] + adh) - m);
    }
    sum = wave_sum(sum);
    float inv = 1.f / (sum + 1e-16f);
    // phase C: accumulate
    float acc = expf(selflogit - m) * inv * h[(size_t)d * C_HC + t];
    for (int e = beg; e < end; ++e) {
        int s = adj_src[e];
        float l = lrelu(a_s[s * C_H + hh] + adh);
        float alpha = expf(l - m) * inv;
        acc += alpha * h[(size_t)s * C_HC + t];
    }
    __shared__ float red[256];
    red[t] = acc;
    __syncthreads();
    if (t < C_CH) {
        float v = (red[t] + red[t + 64] + red[t + 128] + red[t + 192]) * 0.25f + bias1[t];
        h1[(size_t)d * C_CH + t] = fmaxf(v, 0.f);
    }
}

// ---------------- batch-norm stats ----------------
__global__ void k_bnstats(const float* __restrict__ h1, float* __restrict__ bn, int n) {
    int t = threadIdx.x;
    int c = t & 63, rg = t >> 6;
    float s = 0.f, s2 = 0.f;
    for (int r = blockIdx.x * 4 + rg; r < n; r += gridDim.x * 4) {
        float v = h1[(size_t)r * C_CH + c];
        s += v;
        s2 += v * v;
    }
    __shared__ float ls[256], ls2[256];
    ls[t] = s; ls2[t] = s2;
    __syncthreads();
    if (t < 64) {
        s = ls[t] + ls[t + 64] + ls[t + 128] + ls[t + 192];
        s2 = ls2[t] + ls2[t + 64] + ls2[t + 128] + ls2[t + 192];
        atomicAdd(&bn[c], s);
        atomicAdd(&bn[64 + c], s2);
    }
}

__global__ void k_bnfinal(const float* __restrict__ bn, float* __restrict__ mr, int n) {
    int c = threadIdx.x;
    if (c < 64) {
        float mu = bn[c] / n;
        float var = bn[64 + c] / n - mu * mu;
        mr[c] = mu;
        mr[64 + c] = rsqrtf(var + 1e-5f);
    }
}

// ---------------- layer 2 GEMM: x2 = BN(h1) @ W2^T, fused as2/ad2/nf ----------------
__global__ void k_gemm2(const float* __restrict__ h1, const float* __restrict__ W2,
                        const float* __restrict__ att_s, const float* __restrict__ att_d,
                        const float* __restrict__ mr, float* __restrict__ x2,
                        float* __restrict__ as2, float* __restrict__ ad2,
                        float* __restrict__ nf, int n) {
    __shared__ float hs[GROWS * 64];
    __shared__ float nred[C_H][GROWS];
    int r0 = blockIdx.x * GROWS;
    int t = threadIdx.x;
    for (int idx = t; idx < GROWS * 64; idx += 256) {
        int r = idx >> 6, k = idx & 63;
        int rr = r0 + r;
        hs[idx] = (rr < n) ? (h1[(size_t)rr * C_CH + k] - mr[k]) * mr[64 + k] : 0.f;
    }
    __syncthreads();
    int c = t;
    const float4* w4 = (const float4*)(W2 + (size_t)c * C_CH);
    float acc[GROWS];
#pragma unroll
    for (int r = 0; r < GROWS; ++r) acc[r] = 0.f;
    for (int k4 = 0; k4 < 16; ++k4) {
        float4 w = w4[k4];
#pragma unroll
        for (int r = 0; r < GROWS; ++r) {
            float4 xv = *(const float4*)&hs[r * 64 + k4 * 4];
            acc[r] += xv.x * w.x + xv.y * w.y + xv.z * w.z + xv.w * w.w;
        }
    }
    float asc = att_s[c], adc = att_d[c];
    int hh = t >> 6, lane = t & 63;
#pragma unroll
    for (int r = 0; r < GROWS; ++r) {
        int rr = r0 + r;
        if (rr < n) x2[(size_t)rr * C_HC + c] = acc[r];
        float vs = acc[r] * asc, vd = acc[r] * adc, vq = acc[r] * acc[r];
#pragma unroll
        for (int off = 32; off > 0; off >>= 1) {
            vs += __shfl_xor(vs, off);
            vd += __shfl_xor(vd, off);
            vq += __shfl_xor(vq, off);
        }
        if (lane == 0 && rr < n) {
            as2[rr * C_H + hh] = vs;
            ad2[rr * C_H + hh] = vd;
            nred[hh][r] = vq;
        }
    }
    __syncthreads();
    if (t < GROWS) {
        int rr = r0 + t;
        if (rr < n) {
            float q = nred[0][t] + nred[1][t] + nred[2][t] + nred[3][t];
            nf[rr] = fmaxf(sqrtf(q), 1e-8f);
        }
    }
}

// ---------------- node trust + struct norms ----------------
__global__ void k_trust(const float* __restrict__ sf, const float* __restrict__ Wt,
                        const float* __restrict__ bt, float* __restrict__ trust,
                        float* __restrict__ ns, int n) {
    int i = blockIdx.x * blockDim.x + threadIdx.x;
    if (i >= n) return;
    const float4* r4 = (const float4*)(sf + (size_t)i * C_S);
    const float4* w4 = (const float4*)Wt;
    float d = 0.f, q = 0.f;
#pragma unroll
    for (int k = 0; k < 8; ++k) {
        float4 a = r4[k], w = w4[k];
        d += a.x * w.x + a.y * w.y + a.z * w.z + a.w * w.w;
        q += a.x * a.x + a.y * a.y + a.z * a.z + a.w * a.w;
    }
    trust[i] = 1.f / (1.f + expf(-(d + bt[0])));
    ns[i] = fmaxf(sqrtf(q), 1e-8f);
}

// ---------------- per-edge gate logit (wave per edge) ----------------
__global__ void k_gate(const int* __restrict__ srcs, const int* __restrict__ dsts,
                       const float* __restrict__ sf, const float* __restrict__ x2,
                       const float* __restrict__ ns, const float* __restrict__ nf,
                       const float* __restrict__ trust, const float* __restrict__ We1,
                       const float* __restrict__ be1, const float* __restrict__ We2,
                       const float* __restrict__ be2, const float* __restrict__ betas,
                       float* __restrict__ glog, int E) {
    int w = (blockIdx.x * blockDim.x + threadIdx.x) >> 6;
    int lane = threadIdx.x & 63;
    if (w >= E) return;
    int j = srcs[w], i = dsts[w];
    const float4* xj = (const float4*)(x2 + (size_t)j * C_HC);
    const float4* xi = (const float4*)(x2 + (size_t)i * C_HC);
    float4 a = xj[lane], b = xi[lane];
    float fd = a.x * b.x + a.y * b.y + a.z * b.z + a.w * b.w;
    float sd = 0.f;
    if (lane < 8) {
        const float4* sj = (const float4*)(sf + (size_t)j * C_S);
        const float4* si = (const float4*)(sf + (size_t)i * C_S);
        float4 cc = sj[lane], dd = si[lane];
        sd = cc.x * dd.x + cc.y * dd.y + cc.z * dd.z + cc.w * dd.w;
    }
#pragma unroll
    for (int off = 32; off > 0; off >>= 1) {
        fd += __shfl_xor(fd, off);
        sd += __shfl_xor(sd, off);
    }
    if (lane == 0) {
        float ss = sd / (ns[j] * ns[i]);
        float fs = fd / (nf[j] * nf[i]);
        float agr = ss * fs;
        float con = fabsf(ss - fs);
        float gate = be2[0];
#pragma unroll
        for (int o = 0; o < 8; ++o) {
            float hdn = We1[o * 4 + 0] * ss + We1[o * 4 + 1] * fs + We1[o * 4 + 2] * agr +
                        We1[o * 4 + 3] * con + be1[o];
            gate += We2[o] * fmaxf(hdn, 0.f);
        }
        float eb = (1.f / (1.f + expf(-gate))) * fmaxf(agr, 0.f);
        float et = sqrtf(fmaxf(trust[j] * trust[i], 0.f));
        float tb = et * fmaxf(0.5f * (ss + fs), 0.f);
        glog[w] = betas[0] * ss + betas[1] * fs + betas[2] * agr + betas[3] * eb + betas[4] * tb;
    }
}

// ---------------- layer 2 per-dst softmax + aggregate -> out ----------------
__global__ void k_layer2(const int* __restrict__ row_ptr, const int* __restrict__ adj_src,
                         const int* __restrict__ adj_eid, const float* __restrict__ x2,
                         const float* __restrict__ as2, const float* __restrict__ ad2,
                         const float* __restrict__ glog, const float* __restrict__ bias2,
                         float* __restrict__ out) {
    int d = blockIdx.x;
    int t = threadIdx.x, hh = t >> 6, lane = t & 63;
    int beg = row_ptr[d], end = row_ptr[d + 1];
    float adh = ad2[d * C_H + hh];
    float m = -1e30f;
    for (int e = beg + lane; e < end; e += 64) {
        int s = adj_src[e];
        float g = glog[adj_eid[e]];
        m = fmaxf(m, lrelu(as2[s * C_H + hh] + adh) + g);
    }
    m = wave_max(m);
    float sum = 0.f;
    for (int e = beg + lane; e < end; e += 64) {
        int s = adj_src[e];
        float g = glog[adj_eid[e]];
        sum += expf(lrelu(as2[s * C_H + hh] + adh) + g - m);
    }
    sum = wave_sum(sum);
    float inv = 1.f / (sum + 1e-16f);
    float acc = 0.f;
    for (int e = beg; e < end; ++e) {
        int s = adj_src[e];
        float g = glog[adj_eid[e]];
        float l = lrelu(as2[s * C_H + hh] + adh) + g;
        float alpha = expf(l - m) * inv;
        acc += alpha * x2[(size_t)s * C_HC + t];
    }
    __shared__ float red[256];
    red[t] = acc;
    __syncthreads();
    if (t < C_CH) {
        float v = (red[t] + red[t + 64] + red[t + 128] + red[t + 192]) * 0.25f + bias2[t];
        out[(size_t)d * C_CH + t] = v;
    }
}

static inline size_t al256(size_t x) { return (x + 255) & ~(size_t)255; }

extern "C" void kernel_launch(void* const* d_in, const int* in_sizes, int n_in,
                              void* d_out, int out_size, void* d_ws, size_t ws_size,
                              hipStream_t stream) {
    const float* x      = (const float*)d_in[0];
    const int*   ei     = (const int*)d_in[1];
    const float* sf     = (const float*)d_in[2];
    const float* W1     = (const float*)d_in[3];
    const float* atts1  = (const float*)d_in[4];
    const float* attd1  = (const float*)d_in[5];
    const float* bias1  = (const float*)d_in[6];
    const float* W2     = (const float*)d_in[7];
    const float* atts2  = (const float*)d_in[8];
    const float* attd2  = (const float*)d_in[9];
    const float* bias2  = (const float*)d_in[10];
    const float* Wt     = (const float*)d_in[11];
    const float* bt     = (const float*)d_in[12];
    const float* We1    = (const float*)d_in[13];
    const float* be1    = (const float*)d_in[14];
    const float* We2    = (const float*)d_in[15];
    const float* be2    = (const float*)d_in[16];
    const float* betas  = (const float*)d_in[17];

    const int N = in_sizes[0] / C_DIN;
    const int E = in_sizes[1] / 2;
    const int* srcs = ei;
    const int* dsts = ei + E;

    // workspace carve-up (buffers with disjoint lifetimes are aliased to
    // minimize footprint: x2 reuses h; as2/ad2 reuse a_s1/a_d1)
    char* p = (char*)d_ws;
    size_t off = 0;
    auto take = [&](size_t bytes) { char* r = p + off; off = al256(off + bytes); return r; };
    float* h      = (float*)take((size_t)N * C_HC * 4);   // layer-1 h; later reused as x2
    float* h1     = (float*)take((size_t)N * C_CH * 4);
    float* a_s1   = (float*)take((size_t)N * C_H * 4);    // later reused as as2
    float* a_d1   = (float*)take((size_t)N * C_H * 4);    // later reused as ad2
    float* nf     = (float*)take((size_t)N * 4);
    float* ns     = (float*)take((size_t)N * 4);
    float* trust  = (float*)take((size_t)N * 4);
    float* glog   = (float*)take((size_t)E * 4);
    int*   deg    = (int*)take((size_t)N * 4);
    int*   rowp   = (int*)take((size_t)(N + 1) * 4);
    int*   cursor = (int*)take((size_t)N * 4);
    int*   adj_s  = (int*)take((size_t)E * 4);
    int*   adj_e  = (int*)take((size_t)E * 4);
    float* bn     = (float*)take(256 * 4);  // [0:64) sum, [64:128) sumsq, [128:256) mu/rstd
    (void)ws_size;
    float* x2  = h;     // alias: h dead after k_layer1, x2 born in k_gemm2
    float* as2 = a_s1;  // alias: a_s1 dead after k_layer1
    float* ad2 = a_d1;  // alias: a_d1 dead after k_layer1

    hipMemsetAsync(deg, 0, (size_t)N * 4, stream);
    hipMemsetAsync(bn, 0, 128 * 4, stream);

    // CSR build
    k_count<<<(E + 255) / 256, 256, 0, stream>>>(dsts, deg, E);
    k_scan<<<1, 1024, 0, stream>>>(deg, rowp, cursor, N);
    k_scatter<<<(E + 255) / 256, 256, 0, stream>>>(srcs, dsts, cursor, adj_s, adj_e, E);

    // layer 1
    k_gemm1<<<(N + GROWS - 1) / GROWS, 256, 0, stream>>>(x, W1, atts1, attd1, h, a_s1, a_d1, N);
    k_layer1<<<N, 256, 0, stream>>>(rowp, adj_s, h, a_s1, a_d1, bias1, h1);
    k_bnstats<<<128, 256, 0, stream>>>(h1, bn, N);
    k_bnfinal<<<1, 64, 0, stream>>>(bn, bn + 128, N);

    // layer 2
    k_gemm2<<<(N + GROWS - 1) / GROWS, 256, 0, stream>>>(h1, W2, atts2, attd2, bn + 128, x2,
                                                         as2, ad2, nf, N);
    k_trust<<<(N + 255) / 256, 256, 0, stream>>>(sf, Wt, bt, trust, ns, N);
    k_gate<<<(E + 3) / 4, 256, 0, stream>>>(srcs, dsts, sf, x2, ns, nf, trust, We1, be1, We2,
                                            be2, betas, glog, E);
    k_layer2<<<N, 256, 0, stream>>>(rowp, adj_s, adj_e, x2, as2, ad2, glog, bias2, (float*)d_out);
}

// Round 6
// 497.666 us; speedup vs baseline: 1.1627x; 1.1627x over previous
//
#include <hip/hip_runtime.h>
#include <hip/hip_bf16.h>
#include <hip/hip_fp16.h>

// Problem constants (verified against setup_inputs)
#define C_DIN 128
#define C_H 4
#define C_CH 64     // per-head channels (CHID == COUT == 64)
#define C_HC 256    // H * CH
#define C_S 32
#define EPB 64      // edges per block in k_gate

__device__ __forceinline__ float lrelu(float x) { return x >= 0.f ? x : 0.2f * x; }

__device__ __forceinline__ float wave_sum(float v) {
#pragma unroll
    for (int off = 32; off > 0; off >>= 1) v += __shfl_xor(v, off);
    return v;
}
__device__ __forceinline__ float wave_max(float v) {
#pragma unroll
    for (int off = 32; off > 0; off >>= 1) v = fmaxf(v, __shfl_xor(v, off));
    return v;
}

// ---------------- CSR build ----------------
__global__ void k_count(const int* __restrict__ dst, int* __restrict__ deg, int E) {
    int e = blockIdx.x * blockDim.x + threadIdx.x;
    if (e < E) atomicAdd(&deg[dst[e]], 1);
}

// single block of 1024 threads: exclusive scan of deg[0..n) -> row_ptr[0..n], cursor copy
__global__ void k_scan(const int* __restrict__ deg, int* __restrict__ row_ptr,
                       int* __restrict__ cursor, int n) {
    __shared__ int part[1024];
    int t = threadIdx.x;
    const int C = (n + 1023) / 1024;
    int base = t * C;
    int s = 0;
    for (int k = 0; k < C; ++k) {
        int idx = base + k;
        if (idx < n) s += deg[idx];
    }
    part[t] = s;
    __syncthreads();
    for (int off = 1; off < 1024; off <<= 1) {
        int v = (t >= off) ? part[t - off] : 0;
        __syncthreads();
        part[t] += v;
        __syncthreads();
    }
    int run = (t == 0) ? 0 : part[t - 1];
    for (int k = 0; k < C; ++k) {
        int idx = base + k;
        if (idx < n) { row_ptr[idx] = run; cursor[idx] = run; run += deg[idx]; }
    }
    if (t == 1023) row_ptr[n] = run;
}

// scatter: adjacency source list in CSR order + edge->slot map (so k_gate can
// write glog directly in CSR order; k_layer2 then reads it linearly)
__global__ void k_scatter(const int* __restrict__ src, const int* __restrict__ dst,
                          int* __restrict__ cursor, int* __restrict__ adj_src,
                          int* __restrict__ slot, int E) {
    int e = blockIdx.x * blockDim.x + threadIdx.x;
    if (e < E) {
        int d = dst[e];
        int p = atomicAdd(&cursor[d], 1);
        adj_src[p] = src[e];
        slot[e] = p;
    }
}

// ---------------- layer 1 GEMM: h = x @ W1^T (fp16 out), fused a_s1/a_d1 ----------------
#define GROWS 16
__global__ void k_gemm1(const float* __restrict__ x, const float* __restrict__ W1,
                        const float* __restrict__ att_s, const float* __restrict__ att_d,
                        __half* __restrict__ hh_out, float* __restrict__ a_s,
                        float* __restrict__ a_d, int n) {
    __shared__ float4 xs[GROWS * 32];  // 16 rows x 128 cols
    int r0 = blockIdx.x * GROWS;
    int t = threadIdx.x;
    const float4* x4 = (const float4*)x;
    for (int idx = t; idx < GROWS * 32; idx += 256) {
        int r = idx >> 5, k4 = idx & 31;
        int rr = r0 + r;
        xs[idx] = (rr < n) ? x4[(size_t)rr * 32 + k4] : make_float4(0, 0, 0, 0);
    }
    __syncthreads();
    int c = t;  // output column 0..255
    const float4* w4 = (const float4*)(W1 + (size_t)c * C_DIN);
    float acc[GROWS];
#pragma unroll
    for (int r = 0; r < GROWS; ++r) acc[r] = 0.f;
    for (int k4 = 0; k4 < 32; ++k4) {
        float4 w = w4[k4];
#pragma unroll
        for (int r = 0; r < GROWS; ++r) {
            float4 xv = xs[r * 32 + k4];
            acc[r] += xv.x * w.x + xv.y * w.y + xv.z * w.z + xv.w * w.w;
        }
    }
    float asc = att_s[c], adc = att_d[c];
    int hh = t >> 6, lane = t & 63;
#pragma unroll
    for (int r = 0; r < GROWS; ++r) {
        int rr = r0 + r;
        if (rr < n) hh_out[(size_t)rr * C_HC + c] = __float2half(acc[r]);
        float vs = acc[r] * asc, vd = acc[r] * adc;
#pragma unroll
        for (int off = 32; off > 0; off >>= 1) {
            vs += __shfl_xor(vs, off);
            vd += __shfl_xor(vd, off);
        }
        if (lane == 0 && rr < n) { a_s[rr * C_H + hh] = vs; a_d[rr * C_H + hh] = vd; }
    }
}

// ---------------- layer 1 per-dst softmax + aggregate (+self loop) -> h1 ----------------
__global__ void k_layer1(const int* __restrict__ row_ptr, const int* __restrict__ adj_src,
                         const __half* __restrict__ hhlf, const float* __restrict__ a_s,
                         const float* __restrict__ a_d, const float* __restrict__ bias1,
                         float* __restrict__ h1) {
    int d = blockIdx.x;
    int t = threadIdx.x, hh = t >> 6, lane = t & 63;
    int beg = row_ptr[d], end = row_ptr[d + 1];
    float adh = a_d[d * C_H + hh];
    float selflogit = lrelu(a_s[d * C_H + hh] + adh);
    // phase A: max (self included)
    float m = selflogit;
    for (int e = beg + lane; e < end; e += 64) {
        int s = adj_src[e];
        m = fmaxf(m, lrelu(a_s[s * C_H + hh] + adh));
    }
    m = wave_max(m);
    // phase B: sum of exp (self once)
    float sum = (lane == 0) ? expf(selflogit - m) : 0.f;
    for (int e = beg + lane; e < end; e += 64) {
        int s = adj_src[e];
        sum += expf(lrelu(a_s[s * C_H + hh] + adh) - m);
    }
    sum = wave_sum(sum);
    float inv = 1.f / (sum + 1e-16f);
    // phase C: accumulate (fp16 gather rows)
    float acc = expf(selflogit - m) * inv * __half2float(hhlf[(size_t)d * C_HC + t]);
    for (int e = beg; e < end; ++e) {
        int s = adj_src[e];
        float l = lrelu(a_s[s * C_H + hh] + adh);
        float alpha = expf(l - m) * inv;
        acc += alpha * __half2float(hhlf[(size_t)s * C_HC + t]);
    }
    __shared__ float red[256];
    red[t] = acc;
    __syncthreads();
    if (t < C_CH) {
        float v = (red[t] + red[t + 64] + red[t + 128] + red[t + 192]) * 0.25f + bias1[t];
        h1[(size_t)d * C_CH + t] = fmaxf(v, 0.f);
    }
}

// ---------------- batch-norm stats ----------------
__global__ void k_bnstats(const float* __restrict__ h1, float* __restrict__ bn, int n) {
    int t = threadIdx.x;
    int c = t & 63, rg = t >> 6;
    float s = 0.f, s2 = 0.f;
    for (int r = blockIdx.x * 4 + rg; r < n; r += gridDim.x * 4) {
        float v = h1[(size_t)r * C_CH + c];
        s += v;
        s2 += v * v;
    }
    __shared__ float ls[256], ls2[256];
    ls[t] = s; ls2[t] = s2;
    __syncthreads();
    if (t < 64) {
        s = ls[t] + ls[t + 64] + ls[t + 128] + ls[t + 192];
        s2 = ls2[t] + ls2[t + 64] + ls2[t + 128] + ls2[t + 192];
        atomicAdd(&bn[c], s);
        atomicAdd(&bn[64 + c], s2);
    }
}

__global__ void k_bnfinal(const float* __restrict__ bn, float* __restrict__ mr, int n) {
    int c = threadIdx.x;
    if (c < 64) {
        float mu = bn[c] / n;
        float var = bn[64 + c] / n - mu * mu;
        mr[c] = mu;
        mr[64 + c] = rsqrtf(var + 1e-5f);
    }
}

// ---------------- layer 2 GEMM: x2 = BN(h1) @ W2^T (fp16 out), fused as2/ad2/nf ----------------
__global__ void k_gemm2(const float* __restrict__ h1, const float* __restrict__ W2,
                        const float* __restrict__ att_s, const float* __restrict__ att_d,
                        const float* __restrict__ mr, __half* __restrict__ x2h,
                        float* __restrict__ as2, float* __restrict__ ad2,
                        float* __restrict__ nf, int n) {
    __shared__ float hs[GROWS * 64];
    __shared__ float nred[C_H][GROWS];
    int r0 = blockIdx.x * GROWS;
    int t = threadIdx.x;
    for (int idx = t; idx < GROWS * 64; idx += 256) {
        int r = idx >> 6, k = idx & 63;
        int rr = r0 + r;
        hs[idx] = (rr < n) ? (h1[(size_t)rr * C_CH + k] - mr[k]) * mr[64 + k] : 0.f;
    }
    __syncthreads();
    int c = t;
    const float4* w4 = (const float4*)(W2 + (size_t)c * C_CH);
    float acc[GROWS];
#pragma unroll
    for (int r = 0; r < GROWS; ++r) acc[r] = 0.f;
    for (int k4 = 0; k4 < 16; ++k4) {
        float4 w = w4[k4];
#pragma unroll
        for (int r = 0; r < GROWS; ++r) {
            float4 xv = *(const float4*)&hs[r * 64 + k4 * 4];
            acc[r] += xv.x * w.x + xv.y * w.y + xv.z * w.z + xv.w * w.w;
        }
    }
    float asc = att_s[c], adc = att_d[c];
    int hh = t >> 6, lane = t & 63;
#pragma unroll
    for (int r = 0; r < GROWS; ++r) {
        int rr = r0 + r;
        if (rr < n) x2h[(size_t)rr * C_HC + c] = __float2half(acc[r]);
        float vs = acc[r] * asc, vd = acc[r] * adc, vq = acc[r] * acc[r];
#pragma unroll
        for (int off = 32; off > 0; off >>= 1) {
            vs += __shfl_xor(vs, off);
            vd += __shfl_xor(vd, off);
            vq += __shfl_xor(vq, off);
        }
        if (lane == 0 && rr < n) {
            as2[rr * C_H + hh] = vs;
            ad2[rr * C_H + hh] = vd;
            nred[hh][r] = vq;
        }
    }
    __syncthreads();
    if (t < GROWS) {
        int rr = r0 + t;
        if (rr < n) {
            float q = nred[0][t] + nred[1][t] + nred[2][t] + nred[3][t];
            nf[rr] = fmaxf(sqrtf(q), 1e-8f);
        }
    }
}

// ---------------- node trust + struct norms ----------------
__global__ void k_trust(const float* __restrict__ sf, const float* __restrict__ Wt,
                        const float* __restrict__ bt, float* __restrict__ trust,
                        float* __restrict__ ns, int n) {
    int i = blockIdx.x * blockDim.x + threadIdx.x;
    if (i >= n) return;
    const float4* r4 = (const float4*)(sf + (size_t)i * C_S);
    const float4* w4 = (const float4*)Wt;
    float d = 0.f, q = 0.f;
#pragma unroll
    for (int k = 0; k < 8; ++k) {
        float4 a = r4[k], w = w4[k];
        d += a.x * w.x + a.y * w.y + a.z * w.z + a.w * w.w;
        q += a.x * a.x + a.y * a.y + a.z * a.z + a.w * a.w;
    }
    trust[i] = 1.f / (1.f + expf(-(d + bt[0])));
    ns[i] = fmaxf(sqrtf(q), 1e-8f);
}

// ---------------- per-edge gate logit ----------------
// 16 lanes per edge (4 edges per wave, EPB=64 edges per 256-thread block).
// Phase 1: cooperative fp16 row dots -> LDS. Phase 2: scalar tail, one edge
// per thread (parallel instead of wave-serial). Writes glog in CSR order.
__global__ void k_gate(const int* __restrict__ srcs, const int* __restrict__ dsts,
                       const float* __restrict__ sf, const __half* __restrict__ x2h,
                       const float* __restrict__ ns, const float* __restrict__ nf,
                       const float* __restrict__ trust, const float* __restrict__ We1,
                       const float* __restrict__ be1, const float* __restrict__ We2,
                       const float* __restrict__ be2, const float* __restrict__ betas,
                       const int* __restrict__ slot, float* __restrict__ glog, int E) {
    __shared__ float sdL[EPB], fdL[EPB];
    int t = threadIdx.x;
    int w = t >> 6, l = t & 63;
    int g = l >> 4, q = l & 15;     // 16-lane group g, sublane q
    int e0 = blockIdx.x * EPB;
#pragma unroll
    for (int p = 0; p < 4; ++p) {
        int es = p * 16 + w * 4 + g;  // edge slot within block
        int e = e0 + es;
        float fd = 0.f, sd = 0.f;
        if (e < E) {
            int j = srcs[e], i = dsts[e];
            const __half2* aj = (const __half2*)(x2h + (size_t)j * C_HC + q * 16);
            const __half2* bi = (const __half2*)(x2h + (size_t)i * C_HC + q * 16);
            float4 ja = *(const float4*)aj;          // halves 0..7 of this lane's 16
            float4 jb = *(const float4*)(aj + 4);    // halves 8..15
            float4 ia = *(const float4*)bi;
            float4 ib = *(const float4*)(bi + 4);
            const __half2* pja = (const __half2*)&ja;
            const __half2* pjb = (const __half2*)&jb;
            const __half2* pia = (const __half2*)&ia;
            const __half2* pib = (const __half2*)&ib;
#pragma unroll
            for (int k = 0; k < 4; ++k) {
                float2 a = __half22float2(pja[k]), b = __half22float2(pia[k]);
                fd += a.x * b.x + a.y * b.y;
                float2 c = __half22float2(pjb[k]), d = __half22float2(pib[k]);
                fd += c.x * d.x + c.y * d.y;
            }
            float2 sj = *(const float2*)(sf + (size_t)j * C_S + q * 2);
            float2 si = *(const float2*)(sf + (size_t)i * C_S + q * 2);
            sd = sj.x * si.x + sj.y * si.y;
        }
#pragma unroll
        for (int off = 1; off < 16; off <<= 1) {
            fd += __shfl_xor(fd, off);
            sd += __shfl_xor(sd, off);
        }
        if (q == 0) { sdL[es] = sd; fdL[es] = fd; }
    }
    __syncthreads();
    if (t < EPB) {
        int e = e0 + t;
        if (e < E) {
            int j = srcs[e], i = dsts[e];
            float ss = sdL[t] / (ns[j] * ns[i]);
            float fs = fdL[t] / (nf[j] * nf[i]);
            float agr = ss * fs;
            float con = fabsf(ss - fs);
            float gate = be2[0];
#pragma unroll
            for (int o = 0; o < 8; ++o) {
                float hdn = We1[o * 4 + 0] * ss + We1[o * 4 + 1] * fs +
                            We1[o * 4 + 2] * agr + We1[o * 4 + 3] * con + be1[o];
                gate += We2[o] * fmaxf(hdn, 0.f);
            }
            float eb = (1.f / (1.f + expf(-gate))) * fmaxf(agr, 0.f);
            float et = sqrtf(fmaxf(trust[j] * trust[i], 0.f));
            float tb = et * fmaxf(0.5f * (ss + fs), 0.f);
            glog[slot[e]] = betas[0] * ss + betas[1] * fs + betas[2] * agr +
                            betas[3] * eb + betas[4] * tb;
        }
    }
}

// ---------------- layer 2 per-dst softmax + aggregate -> out ----------------
__global__ void k_layer2(const int* __restrict__ row_ptr, const int* __restrict__ adj_src,
                         const __half* __restrict__ x2h, const float* __restrict__ as2,
                         const float* __restrict__ ad2, const float* __restrict__ glog,
                         const float* __restrict__ bias2, float* __restrict__ out) {
    int d = blockIdx.x;
    int t = threadIdx.x, hh = t >> 6, lane = t & 63;
    int beg = row_ptr[d], end = row_ptr[d + 1];
    float adh = ad2[d * C_H + hh];
    float m = -1e30f;
    for (int e = beg + lane; e < end; e += 64) {
        int s = adj_src[e];
        m = fmaxf(m, lrelu(as2[s * C_H + hh] + adh) + glog[e]);
    }
    m = wave_max(m);
    float sum = 0.f;
    for (int e = beg + lane; e < end; e += 64) {
        int s = adj_src[e];
        sum += expf(lrelu(as2[s * C_H + hh] + adh) + glog[e] - m);
    }
    sum = wave_sum(sum);
    float inv = 1.f / (sum + 1e-16f);
    float acc = 0.f;
    for (int e = beg; e < end; ++e) {
        int s = adj_src[e];
        float l = lrelu(as2[s * C_H + hh] + adh) + glog[e];
        float alpha = expf(l - m) * inv;
        acc += alpha * __half2float(x2h[(size_t)s * C_HC + t]);
    }
    __shared__ float red[256];
    red[t] = acc;
    __syncthreads();
    if (t < C_CH) {
        float v = (red[t] + red[t + 64] + red[t + 128] + red[t + 192]) * 0.25f + bias2[t];
        out[(size_t)d * C_CH + t] = v;
    }
}

static inline size_t al256(size_t x) { return (x + 255) & ~(size_t)255; }

extern "C" void kernel_launch(void* const* d_in, const int* in_sizes, int n_in,
                              void* d_out, int out_size, void* d_ws, size_t ws_size,
                              hipStream_t stream) {
    const float* x      = (const float*)d_in[0];
    const int*   ei     = (const int*)d_in[1];
    const float* sf     = (const float*)d_in[2];
    const float* W1     = (const float*)d_in[3];
    const float* atts1  = (const float*)d_in[4];
    const float* attd1  = (const float*)d_in[5];
    const float* bias1  = (const float*)d_in[6];
    const float* W2     = (const float*)d_in[7];
    const float* atts2  = (const float*)d_in[8];
    const float* attd2  = (const float*)d_in[9];
    const float* bias2  = (const float*)d_in[10];
    const float* Wt     = (const float*)d_in[11];
    const float* bt     = (const float*)d_in[12];
    const float* We1    = (const float*)d_in[13];
    const float* be1    = (const float*)d_in[14];
    const float* We2    = (const float*)d_in[15];
    const float* be2    = (const float*)d_in[16];
    const float* betas  = (const float*)d_in[17];

    const int N = in_sizes[0] / C_DIN;
    const int E = in_sizes[1] / 2;
    const int* srcs = ei;
    const int* dsts = ei + E;

    // workspace carve-up; disjoint-lifetime aliases: x2h reuses hhlf,
    // as2/ad2 reuse a_s1/a_d1
    char* p = (char*)d_ws;
    size_t off = 0;
    auto take = [&](size_t bytes) { char* r = p + off; off = al256(off + bytes); return r; };
    __half* hhlf  = (__half*)take((size_t)N * C_HC * 2);  // layer-1 h (fp16); reused as x2h
    float* h1     = (float*)take((size_t)N * C_CH * 4);
    float* a_s1   = (float*)take((size_t)N * C_H * 4);    // reused as as2
    float* a_d1   = (float*)take((size_t)N * C_H * 4);    // reused as ad2
    float* nf     = (float*)take((size_t)N * 4);
    float* ns     = (float*)take((size_t)N * 4);
    float* trust  = (float*)take((size_t)N * 4);
    float* glog   = (float*)take((size_t)E * 4);          // CSR-ordered
    int*   deg    = (int*)take((size_t)N * 4);
    int*   rowp   = (int*)take((size_t)(N + 1) * 4);
    int*   cursor = (int*)take((size_t)N * 4);
    int*   adj_s  = (int*)take((size_t)E * 4);
    int*   slot   = (int*)take((size_t)E * 4);
    float* bn     = (float*)take(256 * 4);  // [0:64) sum, [64:128) sumsq, [128:256) mu/rstd
    (void)ws_size;
    __half* x2h = hhlf;   // alias: hhlf dead after k_layer1, x2h born in k_gemm2
    float* as2  = a_s1;   // alias: a_s1 dead after k_layer1
    float* ad2  = a_d1;   // alias: a_d1 dead after k_layer1

    hipMemsetAsync(deg, 0, (size_t)N * 4, stream);
    hipMemsetAsync(bn, 0, 128 * 4, stream);

    // CSR build
    k_count<<<(E + 255) / 256, 256, 0, stream>>>(dsts, deg, E);
    k_scan<<<1, 1024, 0, stream>>>(deg, rowp, cursor, N);
    k_scatter<<<(E + 255) / 256, 256, 0, stream>>>(srcs, dsts, cursor, adj_s, slot, E);

    // layer 1
    k_gemm1<<<(N + GROWS - 1) / GROWS, 256, 0, stream>>>(x, W1, atts1, attd1, hhlf, a_s1, a_d1, N);
    k_layer1<<<N, 256, 0, stream>>>(rowp, adj_s, hhlf, a_s1, a_d1, bias1, h1);
    k_bnstats<<<128, 256, 0, stream>>>(h1, bn, N);
    k_bnfinal<<<1, 64, 0, stream>>>(bn, bn + 128, N);

    // layer 2
    k_gemm2<<<(N + GROWS - 1) / GROWS, 256, 0, stream>>>(h1, W2, atts2, attd2, bn + 128, x2h,
                                                         as2, ad2, nf, N);
    k_trust<<<(N + 255) / 256, 256, 0, stream>>>(sf, Wt, bt, trust, ns, N);
    k_gate<<<(E + EPB - 1) / EPB, 256, 0, stream>>>(srcs, dsts, sf, x2h, ns, nf, trust,
                                                    We1, be1, We2, be2, betas, slot, glog, E);
    k_layer2<<<N, 256, 0, stream>>>(rowp, adj_s, x2h, as2, ad2, glog, bias2, (float*)d_out);
}

// Round 7
// 383.242 us; speedup vs baseline: 1.5099x; 1.2986x over previous
//
#include <hip/hip_runtime.h>
#include <hip/hip_bf16.h>
#include <hip/hip_fp16.h>

// Problem constants (verified against setup_inputs)
#define C_DIN 128
#define C_H 4
#define C_CH 64     // per-head channels (CHID == COUT == 64)
#define C_HC 256    // H * CH
#define C_S 32
#define EPB 64      // edges per block in k_gate
#define ACH 32      // aggregation chunk (edges) cached in LDS

__device__ __forceinline__ float lrelu(float x) { return x >= 0.f ? x : 0.2f * x; }

__device__ __forceinline__ float wave_sum(float v) {
#pragma unroll
    for (int off = 32; off > 0; off >>= 1) v += __shfl_xor(v, off);
    return v;
}
// reductions confined to 32-lane subgroup (offsets <=16 never cross halves)
__device__ __forceinline__ float sub_sum32(float v) {
#pragma unroll
    for (int off = 16; off > 0; off >>= 1) v += __shfl_xor(v, off);
    return v;
}
__device__ __forceinline__ float sub_max32(float v) {
#pragma unroll
    for (int off = 16; off > 0; off >>= 1) v = fmaxf(v, __shfl_xor(v, off));
    return v;
}

// ---------------- CSR build ----------------
__global__ void k_count(const int* __restrict__ dst, int* __restrict__ deg, int E) {
    int e = blockIdx.x * blockDim.x + threadIdx.x;
    if (e < E) atomicAdd(&deg[dst[e]], 1);
}

__global__ void k_scan(const int* __restrict__ deg, int* __restrict__ row_ptr,
                       int* __restrict__ cursor, int n) {
    __shared__ int part[1024];
    int t = threadIdx.x;
    const int C = (n + 1023) / 1024;
    int base = t * C;
    int s = 0;
    for (int k = 0; k < C; ++k) {
        int idx = base + k;
        if (idx < n) s += deg[idx];
    }
    part[t] = s;
    __syncthreads();
    for (int off = 1; off < 1024; off <<= 1) {
        int v = (t >= off) ? part[t - off] : 0;
        __syncthreads();
        part[t] += v;
        __syncthreads();
    }
    int run = (t == 0) ? 0 : part[t - 1];
    for (int k = 0; k < C; ++k) {
        int idx = base + k;
        if (idx < n) { row_ptr[idx] = run; cursor[idx] = run; run += deg[idx]; }
    }
    if (t == 1023) row_ptr[n] = run;
}

__global__ void k_scatter(const int* __restrict__ src, const int* __restrict__ dst,
                          int* __restrict__ cursor, int* __restrict__ adj_src,
                          int* __restrict__ slot, int E) {
    int e = blockIdx.x * blockDim.x + threadIdx.x;
    if (e < E) {
        int d = dst[e];
        int p = atomicAdd(&cursor[d], 1);
        adj_src[p] = src[e];
        slot[e] = p;
    }
}

// ---------------- layer 1 GEMM: h = x @ W1^T (fp16 out), fused a_s1/a_d1 ----------------
#define GROWS 16
__global__ void k_gemm1(const float* __restrict__ x, const float* __restrict__ W1,
                        const float* __restrict__ att_s, const float* __restrict__ att_d,
                        __half* __restrict__ hh_out, float* __restrict__ a_s,
                        float* __restrict__ a_d, int n) {
    __shared__ float4 xs[GROWS * 32];  // 16 rows x 128 cols
    int r0 = blockIdx.x * GROWS;
    int t = threadIdx.x;
    const float4* x4 = (const float4*)x;
    for (int idx = t; idx < GROWS * 32; idx += 256) {
        int r = idx >> 5, k4 = idx & 31;
        int rr = r0 + r;
        xs[idx] = (rr < n) ? x4[(size_t)rr * 32 + k4] : make_float4(0, 0, 0, 0);
    }
    __syncthreads();
    int c = t;  // output column 0..255
    const float4* w4 = (const float4*)(W1 + (size_t)c * C_DIN);
    float acc[GROWS];
#pragma unroll
    for (int r = 0; r < GROWS; ++r) acc[r] = 0.f;
    for (int k4 = 0; k4 < 32; ++k4) {
        float4 w = w4[k4];
#pragma unroll
        for (int r = 0; r < GROWS; ++r) {
            float4 xv = xs[r * 32 + k4];
            acc[r] += xv.x * w.x + xv.y * w.y + xv.z * w.z + xv.w * w.w;
        }
    }
    float asc = att_s[c], adc = att_d[c];
    int hh = t >> 6, lane = t & 63;
#pragma unroll
    for (int r = 0; r < GROWS; ++r) {
        int rr = r0 + r;
        if (rr < n) hh_out[(size_t)rr * C_HC + c] = __float2half(acc[r]);
        float vs = acc[r] * asc, vd = acc[r] * adc;
#pragma unroll
        for (int off = 32; off > 0; off >>= 1) {
            vs += __shfl_xor(vs, off);
            vd += __shfl_xor(vd, off);
        }
        if (lane == 0 && rr < n) { a_s[rr * C_H + hh] = vs; a_d[rr * C_H + hh] = vd; }
    }
}

// ---------------- layer 1 aggregation: 128 threads / node, LDS-cached alpha ----------------
// thread t: head hh=t>>5, channel pair cp=t&31 -> channels hh*64 + cp*2 (+1)
__global__ void k_layer1(const int* __restrict__ row_ptr, const int* __restrict__ adj_src,
                         const __half* __restrict__ hhlf, const float* __restrict__ a_s,
                         const float* __restrict__ a_d, const float* __restrict__ bias1,
                         float* __restrict__ h1) {
    int d = blockIdx.x;
    int t = threadIdx.x, hh = t >> 5, cp = t & 31;
    int beg = row_ptr[d], end = row_ptr[d + 1];
    float adh = a_d[d * C_H + hh];
    float self = lrelu(a_s[d * C_H + hh] + adh);
    // phase A: per-head max (self included), 32-lane strided
    float m = self;
    for (int e = beg + cp; e < end; e += 32)
        m = fmaxf(m, lrelu(a_s[adj_src[e] * C_H + hh] + adh));
    m = sub_max32(m);
    // phase B: sum of exp (self once)
    float sum = (cp == 0) ? expf(self - m) : 0.f;
    for (int e = beg + cp; e < end; e += 32)
        sum += expf(lrelu(a_s[adj_src[e] * C_H + hh] + adh) - m);
    sum = sub_sum32(sum);
    float inv = 1.f / (sum + 1e-16f);
    // phase C: chunks of 32 edges; alpha+src staged in LDS
    __shared__ float alpha_l[C_H][ACH];
    __shared__ int src_l[ACH];
    const __half2* selfrow = (const __half2*)(hhlf + (size_t)d * C_HC + hh * 64);
    float sa = expf(self - m) * inv;
    float2 sv = __half22float2(selfrow[cp]);
    float accx = sa * sv.x, accy = sa * sv.y;
    for (int cbeg = beg; cbeg < end; cbeg += ACH) {
        int cn = min(end - cbeg, ACH);
        __syncthreads();  // previous chunk fully consumed
        if (cp < cn) {
            int s = adj_src[cbeg + cp];
            if (hh == 0) src_l[cp] = s;
            alpha_l[hh][cp] = expf(lrelu(a_s[s * C_H + hh] + adh) - m) * inv;
        }
        __syncthreads();
        for (int i = 0; i < cn; ++i) {
            int s = src_l[i];
            float a = alpha_l[hh][i];
            float2 v = __half22float2(
                *(const __half2*)(hhlf + (size_t)s * C_HC + hh * 64 + cp * 2));
            accx += a * v.x;
            accy += a * v.y;
        }
    }
    __shared__ float2 red[128];
    red[t] = make_float2(accx, accy);
    __syncthreads();
    if (t < 32) {
        float2 r0 = red[t], r1 = red[t + 32], r2 = red[t + 64], r3 = red[t + 96];
        float2 b = *(const float2*)&bias1[t * 2];
        float vx = (r0.x + r1.x + r2.x + r3.x) * 0.25f + b.x;
        float vy = (r0.y + r1.y + r2.y + r3.y) * 0.25f + b.y;
        *(float2*)&h1[(size_t)d * C_CH + t * 2] =
            make_float2(fmaxf(vx, 0.f), fmaxf(vy, 0.f));
    }
}

// ---------------- batch-norm stats ----------------
__global__ void k_bnstats(const float* __restrict__ h1, float* __restrict__ bn, int n) {
    int t = threadIdx.x;
    int c = t & 63, rg = t >> 6;
    float s = 0.f, s2 = 0.f;
    for (int r = blockIdx.x * 4 + rg; r < n; r += gridDim.x * 4) {
        float v = h1[(size_t)r * C_CH + c];
        s += v;
        s2 += v * v;
    }
    __shared__ float ls[256], ls2[256];
    ls[t] = s; ls2[t] = s2;
    __syncthreads();
    if (t < 64) {
        s = ls[t] + ls[t + 64] + ls[t + 128] + ls[t + 192];
        s2 = ls2[t] + ls2[t + 64] + ls2[t + 128] + ls2[t + 192];
        atomicAdd(&bn[c], s);
        atomicAdd(&bn[64 + c], s2);
    }
}

__global__ void k_bnfinal(const float* __restrict__ bn, float* __restrict__ mr, int n) {
    int c = threadIdx.x;
    if (c < 64) {
        float mu = bn[c] / n;
        float var = bn[64 + c] / n - mu * mu;
        mr[c] = mu;
        mr[64 + c] = rsqrtf(var + 1e-5f);
    }
}

// ---------------- layer 2 GEMM: x2 = BN(h1) @ W2^T (fp16 out), fused as2/ad2/nf ----------------
__global__ void k_gemm2(const float* __restrict__ h1, const float* __restrict__ W2,
                        const float* __restrict__ att_s, const float* __restrict__ att_d,
                        const float* __restrict__ mr, __half* __restrict__ x2h,
                        float* __restrict__ as2, float* __restrict__ ad2,
                        float* __restrict__ nf, int n) {
    __shared__ float hs[GROWS * 64];
    __shared__ float nred[C_H][GROWS];
    int r0 = blockIdx.x * GROWS;
    int t = threadIdx.x;
    for (int idx = t; idx < GROWS * 64; idx += 256) {
        int r = idx >> 6, k = idx & 63;
        int rr = r0 + r;
        hs[idx] = (rr < n) ? (h1[(size_t)rr * C_CH + k] - mr[k]) * mr[64 + k] : 0.f;
    }
    __syncthreads();
    int c = t;
    const float4* w4 = (const float4*)(W2 + (size_t)c * C_CH);
    float acc[GROWS];
#pragma unroll
    for (int r = 0; r < GROWS; ++r) acc[r] = 0.f;
    for (int k4 = 0; k4 < 16; ++k4) {
        float4 w = w4[k4];
#pragma unroll
        for (int r = 0; r < GROWS; ++r) {
            float4 xv = *(const float4*)&hs[r * 64 + k4 * 4];
            acc[r] += xv.x * w.x + xv.y * w.y + xv.z * w.z + xv.w * w.w;
        }
    }
    float asc = att_s[c], adc = att_d[c];
    int hh = t >> 6, lane = t & 63;
#pragma unroll
    for (int r = 0; r < GROWS; ++r) {
        int rr = r0 + r;
        if (rr < n) x2h[(size_t)rr * C_HC + c] = __float2half(acc[r]);
        float vs = acc[r] * asc, vd = acc[r] * adc, vq = acc[r] * acc[r];
#pragma unroll
        for (int off = 32; off > 0; off >>= 1) {
            vs += __shfl_xor(vs, off);
            vd += __shfl_xor(vd, off);
            vq += __shfl_xor(vq, off);
        }
        if (lane == 0 && rr < n) {
            as2[rr * C_H + hh] = vs;
            ad2[rr * C_H + hh] = vd;
            nred[hh][r] = vq;
        }
    }
    __syncthreads();
    if (t < GROWS) {
        int rr = r0 + t;
        if (rr < n) {
            float q = nred[0][t] + nred[1][t] + nred[2][t] + nred[3][t];
            nf[rr] = fmaxf(sqrtf(q), 1e-8f);
        }
    }
}

// ---------------- node trust + struct norms ----------------
__global__ void k_trust(const float* __restrict__ sf, const float* __restrict__ Wt,
                        const float* __restrict__ bt, float* __restrict__ trust,
                        float* __restrict__ ns, int n) {
    int i = blockIdx.x * blockDim.x + threadIdx.x;
    if (i >= n) return;
    const float4* r4 = (const float4*)(sf + (size_t)i * C_S);
    const float4* w4 = (const float4*)Wt;
    float d = 0.f, q = 0.f;
#pragma unroll
    for (int k = 0; k < 8; ++k) {
        float4 a = r4[k], w = w4[k];
        d += a.x * w.x + a.y * w.y + a.z * w.z + a.w * w.w;
        q += a.x * a.x + a.y * a.y + a.z * a.z + a.w * a.w;
    }
    trust[i] = 1.f / (1.f + expf(-(d + bt[0])));
    ns[i] = fmaxf(sqrtf(q), 1e-8f);
}

// ---------------- per-edge gate logit ----------------
__global__ void k_gate(const int* __restrict__ srcs, const int* __restrict__ dsts,
                       const float* __restrict__ sf, const __half* __restrict__ x2h,
                       const float* __restrict__ ns, const float* __restrict__ nf,
                       const float* __restrict__ trust, const float* __restrict__ We1,
                       const float* __restrict__ be1, const float* __restrict__ We2,
                       const float* __restrict__ be2, const float* __restrict__ betas,
                       const int* __restrict__ slot, float* __restrict__ glog, int E) {
    __shared__ float sdL[EPB], fdL[EPB];
    int t = threadIdx.x;
    int w = t >> 6, l = t & 63;
    int g = l >> 4, q = l & 15;     // 16-lane group g, sublane q
    int e0 = blockIdx.x * EPB;
#pragma unroll
    for (int p = 0; p < 4; ++p) {
        int es = p * 16 + w * 4 + g;  // edge slot within block
        int e = e0 + es;
        float fd = 0.f, sd = 0.f;
        if (e < E) {
            int j = srcs[e], i = dsts[e];
            const __half2* aj = (const __half2*)(x2h + (size_t)j * C_HC + q * 16);
            const __half2* bi = (const __half2*)(x2h + (size_t)i * C_HC + q * 16);
            float4 ja = *(const float4*)aj;          // halves 0..7 of this lane's 16
            float4 jb = *(const float4*)(aj + 4);    // halves 8..15
            float4 ia = *(const float4*)bi;
            float4 ib = *(const float4*)(bi + 4);
            const __half2* pja = (const __half2*)&ja;
            const __half2* pjb = (const __half2*)&jb;
            const __half2* pia = (const __half2*)&ia;
            const __half2* pib = (const __half2*)&ib;
#pragma unroll
            for (int k = 0; k < 4; ++k) {
                float2 a = __half22float2(pja[k]), b = __half22float2(pia[k]);
                fd += a.x * b.x + a.y * b.y;
                float2 c = __half22float2(pjb[k]), d = __half22float2(pib[k]);
                fd += c.x * d.x + c.y * d.y;
            }
            float2 sj = *(const float2*)(sf + (size_t)j * C_S + q * 2);
            float2 si = *(const float2*)(sf + (size_t)i * C_S + q * 2);
            sd = sj.x * si.x + sj.y * si.y;
        }
#pragma unroll
        for (int off = 1; off < 16; off <<= 1) {
            fd += __shfl_xor(fd, off);
            sd += __shfl_xor(sd, off);
        }
        if (q == 0) { sdL[es] = sd; fdL[es] = fd; }
    }
    __syncthreads();
    if (t < EPB) {
        int e = e0 + t;
        if (e < E) {
            int j = srcs[e], i = dsts[e];
            float ss = sdL[t] / (ns[j] * ns[i]);
            float fs = fdL[t] / (nf[j] * nf[i]);
            float agr = ss * fs;
            float con = fabsf(ss - fs);
            float gate = be2[0];
#pragma unroll
            for (int o = 0; o < 8; ++o) {
                float hdn = We1[o * 4 + 0] * ss + We1[o * 4 + 1] * fs +
                            We1[o * 4 + 2] * agr + We1[o * 4 + 3] * con + be1[o];
                gate += We2[o] * fmaxf(hdn, 0.f);
            }
            float eb = (1.f / (1.f + expf(-gate))) * fmaxf(agr, 0.f);
            float et = sqrtf(fmaxf(trust[j] * trust[i], 0.f));
            float tb = et * fmaxf(0.5f * (ss + fs), 0.f);
            glog[slot[e]] = betas[0] * ss + betas[1] * fs + betas[2] * agr +
                            betas[3] * eb + betas[4] * tb;
        }
    }
}

// ---------------- layer 2 aggregation: 128 threads / node, LDS-cached alpha ----------------
__global__ void k_layer2(const int* __restrict__ row_ptr, const int* __restrict__ adj_src,
                         const __half* __restrict__ x2h, const float* __restrict__ as2,
                         const float* __restrict__ ad2, const float* __restrict__ glog,
                         const float* __restrict__ bias2, float* __restrict__ out) {
    int d = blockIdx.x;
    int t = threadIdx.x, hh = t >> 5, cp = t & 31;
    int beg = row_ptr[d], end = row_ptr[d + 1];
    float adh = ad2[d * C_H + hh];
    // phase A: max
    float m = -1e30f;
    for (int e = beg + cp; e < end; e += 32)
        m = fmaxf(m, lrelu(as2[adj_src[e] * C_H + hh] + adh) + glog[e]);
    m = sub_max32(m);
    // phase B: sum of exp
    float sum = 0.f;
    for (int e = beg + cp; e < end; e += 32)
        sum += expf(lrelu(as2[adj_src[e] * C_H + hh] + adh) + glog[e] - m);
    sum = sub_sum32(sum);
    float inv = 1.f / (sum + 1e-16f);
    // phase C
    __shared__ float alpha_l[C_H][ACH];
    __shared__ int src_l[ACH];
    float accx = 0.f, accy = 0.f;
    for (int cbeg = beg; cbeg < end; cbeg += ACH) {
        int cn = min(end - cbeg, ACH);
        __syncthreads();
        if (cp < cn) {
            int s = adj_src[cbeg + cp];
            if (hh == 0) src_l[cp] = s;
            alpha_l[hh][cp] =
                expf(lrelu(as2[s * C_H + hh] + adh) + glog[cbeg + cp] - m) * inv;
        }
        __syncthreads();
        for (int i = 0; i < cn; ++i) {
            int s = src_l[i];
            float a = alpha_l[hh][i];
            float2 v = __half22float2(
                *(const __half2*)(x2h + (size_t)s * C_HC + hh * 64 + cp * 2));
            accx += a * v.x;
            accy += a * v.y;
        }
    }
    __shared__ float2 red[128];
    red[t] = make_float2(accx, accy);
    __syncthreads();
    if (t < 32) {
        float2 r0 = red[t], r1 = red[t + 32], r2 = red[t + 64], r3 = red[t + 96];
        float2 b = *(const float2*)&bias2[t * 2];
        float vx = (r0.x + r1.x + r2.x + r3.x) * 0.25f + b.x;
        float vy = (r0.y + r1.y + r2.y + r3.y) * 0.25f + b.y;
        *(float2*)&out[(size_t)d * C_CH + t * 2] = make_float2(vx, vy);
    }
}

static inline size_t al256(size_t x) { return (x + 255) & ~(size_t)255; }

extern "C" void kernel_launch(void* const* d_in, const int* in_sizes, int n_in,
                              void* d_out, int out_size, void* d_ws, size_t ws_size,
                              hipStream_t stream) {
    const float* x      = (const float*)d_in[0];
    const int*   ei     = (const int*)d_in[1];
    const float* sf     = (const float*)d_in[2];
    const float* W1     = (const float*)d_in[3];
    const float* atts1  = (const float*)d_in[4];
    const float* attd1  = (const float*)d_in[5];
    const float* bias1  = (const float*)d_in[6];
    const float* W2     = (const float*)d_in[7];
    const float* atts2  = (const float*)d_in[8];
    const float* attd2  = (const float*)d_in[9];
    const float* bias2  = (const float*)d_in[10];
    const float* Wt     = (const float*)d_in[11];
    const float* bt     = (const float*)d_in[12];
    const float* We1    = (const float*)d_in[13];
    const float* be1    = (const float*)d_in[14];
    const float* We2    = (const float*)d_in[15];
    const float* be2    = (const float*)d_in[16];
    const float* betas  = (const float*)d_in[17];

    const int N = in_sizes[0] / C_DIN;
    const int E = in_sizes[1] / 2;
    const int* srcs = ei;
    const int* dsts = ei + E;

    // workspace carve-up; disjoint-lifetime aliases: x2h reuses hhlf,
    // as2/ad2 reuse a_s1/a_d1
    char* p = (char*)d_ws;
    size_t off = 0;
    auto take = [&](size_t bytes) { char* r = p + off; off = al256(off + bytes); return r; };
    __half* hhlf  = (__half*)take((size_t)N * C_HC * 2);  // layer-1 h (fp16); reused as x2h
    float* h1     = (float*)take((size_t)N * C_CH * 4);
    float* a_s1   = (float*)take((size_t)N * C_H * 4);    // reused as as2
    float* a_d1   = (float*)take((size_t)N * C_H * 4);    // reused as ad2
    float* nf     = (float*)take((size_t)N * 4);
    float* ns     = (float*)take((size_t)N * 4);
    float* trust  = (float*)take((size_t)N * 4);
    float* glog   = (float*)take((size_t)E * 4);          // CSR-ordered
    int*   deg    = (int*)take((size_t)N * 4);
    int*   rowp   = (int*)take((size_t)(N + 1) * 4);
    int*   cursor = (int*)take((size_t)N * 4);
    int*   adj_s  = (int*)take((size_t)E * 4);
    int*   slot   = (int*)take((size_t)E * 4);
    float* bn     = (float*)take(256 * 4);  // [0:64) sum, [64:128) sumsq, [128:256) mu/rstd
    (void)ws_size;
    __half* x2h = hhlf;   // alias: hhlf dead after k_layer1, x2h born in k_gemm2
    float* as2  = a_s1;   // alias: a_s1 dead after k_layer1
    float* ad2  = a_d1;   // alias: a_d1 dead after k_layer1

    hipMemsetAsync(deg, 0, (size_t)N * 4, stream);
    hipMemsetAsync(bn, 0, 128 * 4, stream);

    // CSR build
    k_count<<<(E + 255) / 256, 256, 0, stream>>>(dsts, deg, E);
    k_scan<<<1, 1024, 0, stream>>>(deg, rowp, cursor, N);
    k_scatter<<<(E + 255) / 256, 256, 0, stream>>>(srcs, dsts, cursor, adj_s, slot, E);

    // layer 1
    k_gemm1<<<(N + GROWS - 1) / GROWS, 256, 0, stream>>>(x, W1, atts1, attd1, hhlf, a_s1, a_d1, N);
    k_layer1<<<N, 128, 0, stream>>>(rowp, adj_s, hhlf, a_s1, a_d1, bias1, h1);
    k_bnstats<<<128, 256, 0, stream>>>(h1, bn, N);
    k_bnfinal<<<1, 64, 0, stream>>>(bn, bn + 128, N);

    // layer 2
    k_gemm2<<<(N + GROWS - 1) / GROWS, 256, 0, stream>>>(h1, W2, atts2, attd2, bn + 128, x2h,
                                                         as2, ad2, nf, N);
    k_trust<<<(N + 255) / 256, 256, 0, stream>>>(sf, Wt, bt, trust, ns, N);
    k_gate<<<(E + EPB - 1) / EPB, 256, 0, stream>>>(srcs, dsts, sf, x2h, ns, nf, trust,
                                                    We1, be1, We2, be2, betas, slot, glog, E);
    k_layer2<<<N, 128, 0, stream>>>(rowp, adj_s, x2h, as2, ad2, glog, bias2, (float*)d_out);
}

// Round 8
// 336.632 us; speedup vs baseline: 1.7189x; 1.1385x over previous
//
#include <hip/hip_runtime.h>
#include <hip/hip_bf16.h>
#include <hip/hip_fp16.h>

// Problem constants (verified against setup_inputs)
#define C_DIN 128
#define C_H 4
#define C_CH 64     // per-head channels (CHID == COUT == 64)
#define C_HC 256    // H * CH
#define C_S 32
#define EPB 64      // edges per block in k_gate
#define ACH 32      // aggregation chunk (edges) cached in LDS
#define MBLK 64     // GEMM M-tile (rows per block)

typedef __attribute__((ext_vector_type(8))) _Float16 half8;
typedef __attribute__((ext_vector_type(4))) float f32x4;

__device__ __forceinline__ float lrelu(float x) { return x >= 0.f ? x : 0.2f * x; }

// reductions confined to 32-lane subgroup (offsets <=16 never cross halves)
__device__ __forceinline__ float sub_sum32(float v) {
#pragma unroll
    for (int off = 16; off > 0; off >>= 1) v += __shfl_xor(v, off);
    return v;
}
__device__ __forceinline__ float sub_max32(float v) {
#pragma unroll
    for (int off = 16; off > 0; off >>= 1) v = fmaxf(v, __shfl_xor(v, off));
    return v;
}

// ---------------- CSR build ----------------
__global__ void k_count(const int* __restrict__ dst, int* __restrict__ deg, int E) {
    int e = blockIdx.x * blockDim.x + threadIdx.x;
    if (e < E) atomicAdd(&deg[dst[e]], 1);
}

__global__ void k_scan(const int* __restrict__ deg, int* __restrict__ row_ptr,
                       int* __restrict__ cursor, int n) {
    __shared__ int part[1024];
    int t = threadIdx.x;
    const int C = (n + 1023) / 1024;
    int base = t * C;
    int s = 0;
    for (int k = 0; k < C; ++k) {
        int idx = base + k;
        if (idx < n) s += deg[idx];
    }
    part[t] = s;
    __syncthreads();
    for (int off = 1; off < 1024; off <<= 1) {
        int v = (t >= off) ? part[t - off] : 0;
        __syncthreads();
        part[t] += v;
        __syncthreads();
    }
    int run = (t == 0) ? 0 : part[t - 1];
    for (int k = 0; k < C; ++k) {
        int idx = base + k;
        if (idx < n) { row_ptr[idx] = run; cursor[idx] = run; run += deg[idx]; }
    }
    if (t == 1023) row_ptr[n] = run;
}

__global__ void k_scatter(const int* __restrict__ src, const int* __restrict__ dst,
                          int* __restrict__ cursor, int* __restrict__ adj_src,
                          int* __restrict__ slot, int E) {
    int e = blockIdx.x * blockDim.x + threadIdx.x;
    if (e < E) {
        int d = dst[e];
        int p = atomicAdd(&cursor[d], 1);
        adj_src[p] = src[e];
        slot[e] = p;
    }
}

// ---------------- layer 1 GEMM (MFMA fp16): h = x @ W1^T, fused a_s1/a_d1 ----------------
// 4 waves/block; wave w owns cols [w*64, w*64+64) == head w. M_BLK=64 rows.
// LDS pre-swizzled: fragment loads are single conflict-free ds_read_b128.
// Fragment layout (m89-verified family): A[l&15][(l>>4)*8+t], B[(l>>4)*8+t][l&15],
// D row=(l>>4)*4+reg, col=l&15.
__global__ __launch_bounds__(256) void k_gemm1(
    const float* __restrict__ x, const float* __restrict__ W1,
    const float* __restrict__ att_s, const float* __restrict__ att_d,
    __half* __restrict__ hh_out, float* __restrict__ a_s, float* __restrict__ a_d, int n) {
    __shared__ __align__(16) _Float16 bs[4 * 16 * 64 * 8];  // [ks][ntg][lane][8] = 64 KB
    __shared__ __align__(16) _Float16 as_[4 * 4 * 64 * 8];  // [ks][mt][lane][8]  = 16 KB
    int t = threadIdx.x;
    int r0 = blockIdx.x * MBLK;
    // stage B = W1^T (fp32 -> fp16): thread t handles W1 row c=t (128 floats, 16 chunks of 8)
    {
        int c = t;
        const float4* wrow = (const float4*)(W1 + (size_t)c * C_DIN);
        int nt = c >> 4, cl = c & 15;
#pragma unroll
        for (int ch = 0; ch < 16; ++ch) {
            float4 f0 = wrow[ch * 2], f1 = wrow[ch * 2 + 1];
            int ks = ch >> 2, lg = ch & 3;
            _Float16* dst = &bs[(((ks * 16 + nt) * 64) + (lg * 16 + cl)) * 8];
            dst[0] = (_Float16)f0.x; dst[1] = (_Float16)f0.y;
            dst[2] = (_Float16)f0.z; dst[3] = (_Float16)f0.w;
            dst[4] = (_Float16)f1.x; dst[5] = (_Float16)f1.y;
            dst[6] = (_Float16)f1.z; dst[7] = (_Float16)f1.w;
        }
    }
    // stage A = x rows (fp32 -> fp16): row = t>>2, 4 chunks of 8 per thread
    {
        int row = t >> 2, q = t & 3;
        int rr = r0 + row;
        int mt = row >> 4, rl = row & 15;
        const float4* xrow = (const float4*)(x + (size_t)rr * C_DIN);
#pragma unroll
        for (int cc = 0; cc < 4; ++cc) {
            int ch = q * 4 + cc;
            float4 f0 = make_float4(0, 0, 0, 0), f1 = make_float4(0, 0, 0, 0);
            if (rr < n) { f0 = xrow[ch * 2]; f1 = xrow[ch * 2 + 1]; }
            int ks = ch >> 2, lg = ch & 3;
            _Float16* dst = &as_[(((ks * 4 + mt) * 64) + (lg * 16 + rl)) * 8];
            dst[0] = (_Float16)f0.x; dst[1] = (_Float16)f0.y;
            dst[2] = (_Float16)f0.z; dst[3] = (_Float16)f0.w;
            dst[4] = (_Float16)f1.x; dst[5] = (_Float16)f1.y;
            dst[6] = (_Float16)f1.z; dst[7] = (_Float16)f1.w;
        }
    }
    __syncthreads();
    int w = t >> 6, l = t & 63;
    f32x4 acc[4][4];
#pragma unroll
    for (int mt = 0; mt < 4; ++mt)
#pragma unroll
        for (int nt = 0; nt < 4; ++nt) acc[mt][nt] = (f32x4){0.f, 0.f, 0.f, 0.f};
#pragma unroll
    for (int ks = 0; ks < 4; ++ks) {
        half8 af[4], bf[4];
#pragma unroll
        for (int mt = 0; mt < 4; ++mt)
            af[mt] = *(const half8*)&as_[(((ks * 4 + mt) * 64) + l) * 8];
#pragma unroll
        for (int nt = 0; nt < 4; ++nt)
            bf[nt] = *(const half8*)&bs[(((ks * 16 + (w * 4 + nt)) * 64) + l) * 8];
#pragma unroll
        for (int mt = 0; mt < 4; ++mt)
#pragma unroll
            for (int nt = 0; nt < 4; ++nt)
                acc[mt][nt] = __builtin_amdgcn_mfma_f32_16x16x32_f16(af[mt], bf[nt],
                                                                     acc[mt][nt], 0, 0, 0);
    }
    // epilogue: h (fp16) + per-head a_s/a_d (head == wave)
    int cl = l & 15, rg = l >> 4;
    float atv_s[4], atv_d[4];
#pragma unroll
    for (int nt = 0; nt < 4; ++nt) {
        atv_s[nt] = att_s[w * 64 + nt * 16 + cl];
        atv_d[nt] = att_d[w * 64 + nt * 16 + cl];
    }
#pragma unroll
    for (int mt = 0; mt < 4; ++mt) {
#pragma unroll
        for (int r = 0; r < 4; ++r) {
            int rr = r0 + mt * 16 + rg * 4 + r;
            float vs = 0.f, vd = 0.f;
#pragma unroll
            for (int nt = 0; nt < 4; ++nt) {
                float v = acc[mt][nt][r];
                vs += atv_s[nt] * v;
                vd += atv_d[nt] * v;
                if (rr < n)
                    hh_out[(size_t)rr * C_HC + w * 64 + nt * 16 + cl] = __float2half(v);
            }
#pragma unroll
            for (int off = 1; off < 16; off <<= 1) {
                vs += __shfl_xor(vs, off);
                vd += __shfl_xor(vd, off);
            }
            if (cl == 0 && rr < n) { a_s[rr * C_H + w] = vs; a_d[rr * C_H + w] = vd; }
        }
    }
}

// ---------------- layer 1 aggregation: 128 threads / node, LDS-cached alpha ----------------
__global__ void k_layer1(const int* __restrict__ row_ptr, const int* __restrict__ adj_src,
                         const __half* __restrict__ hhlf, const float* __restrict__ a_s,
                         const float* __restrict__ a_d, const float* __restrict__ bias1,
                         float* __restrict__ h1) {
    int d = blockIdx.x;
    int t = threadIdx.x, hh = t >> 5, cp = t & 31;
    int beg = row_ptr[d], end = row_ptr[d + 1];
    float adh = a_d[d * C_H + hh];
    float self = lrelu(a_s[d * C_H + hh] + adh);
    float m = self;
    for (int e = beg + cp; e < end; e += 32)
        m = fmaxf(m, lrelu(a_s[adj_src[e] * C_H + hh] + adh));
    m = sub_max32(m);
    float sum = (cp == 0) ? expf(self - m) : 0.f;
    for (int e = beg + cp; e < end; e += 32)
        sum += expf(lrelu(a_s[adj_src[e] * C_H + hh] + adh) - m);
    sum = sub_sum32(sum);
    float inv = 1.f / (sum + 1e-16f);
    __shared__ float alpha_l[C_H][ACH];
    __shared__ int src_l[ACH];
    const __half2* selfrow = (const __half2*)(hhlf + (size_t)d * C_HC + hh * 64);
    float sa = expf(self - m) * inv;
    float2 sv = __half22float2(selfrow[cp]);
    float accx = sa * sv.x, accy = sa * sv.y;
    for (int cbeg = beg; cbeg < end; cbeg += ACH) {
        int cn = min(end - cbeg, ACH);
        __syncthreads();
        if (cp < cn) {
            int s = adj_src[cbeg + cp];
            if (hh == 0) src_l[cp] = s;
            alpha_l[hh][cp] = expf(lrelu(a_s[s * C_H + hh] + adh) - m) * inv;
        }
        __syncthreads();
        for (int i = 0; i < cn; ++i) {
            int s = src_l[i];
            float a = alpha_l[hh][i];
            float2 v = __half22float2(
                *(const __half2*)(hhlf + (size_t)s * C_HC + hh * 64 + cp * 2));
            accx += a * v.x;
            accy += a * v.y;
        }
    }
    __shared__ float2 red[128];
    red[t] = make_float2(accx, accy);
    __syncthreads();
    if (t < 32) {
        float2 r0 = red[t], r1 = red[t + 32], r2 = red[t + 64], r3 = red[t + 96];
        float2 b = *(const float2*)&bias1[t * 2];
        float vx = (r0.x + r1.x + r2.x + r3.x) * 0.25f + b.x;
        float vy = (r0.y + r1.y + r2.y + r3.y) * 0.25f + b.y;
        *(float2*)&h1[(size_t)d * C_CH + t * 2] =
            make_float2(fmaxf(vx, 0.f), fmaxf(vy, 0.f));
    }
}

// ---------------- batch-norm stats ----------------
__global__ void k_bnstats(const float* __restrict__ h1, float* __restrict__ bn, int n) {
    int t = threadIdx.x;
    int c = t & 63, rg = t >> 6;
    float s = 0.f, s2 = 0.f;
    for (int r = blockIdx.x * 4 + rg; r < n; r += gridDim.x * 4) {
        float v = h1[(size_t)r * C_CH + c];
        s += v;
        s2 += v * v;
    }
    __shared__ float ls[256], ls2[256];
    ls[t] = s; ls2[t] = s2;
    __syncthreads();
    if (t < 64) {
        s = ls[t] + ls[t + 64] + ls[t + 128] + ls[t + 192];
        s2 = ls2[t] + ls2[t + 64] + ls2[t + 128] + ls2[t + 192];
        atomicAdd(&bn[c], s);
        atomicAdd(&bn[64 + c], s2);
    }
}

__global__ void k_bnfinal(const float* __restrict__ bn, float* __restrict__ mr, int n) {
    int c = threadIdx.x;
    if (c < 64) {
        float mu = bn[c] / n;
        float var = bn[64 + c] / n - mu * mu;
        mr[c] = mu;
        mr[64 + c] = rsqrtf(var + 1e-5f);
    }
}

// ---------------- layer 2 GEMM (MFMA fp16): x2 = BN(h1) @ W2^T, fused as2/ad2/nf ----------
__global__ __launch_bounds__(256) void k_gemm2(
    const float* __restrict__ h1, const float* __restrict__ W2,
    const float* __restrict__ att_s, const float* __restrict__ att_d,
    const float* __restrict__ mr, __half* __restrict__ x2h,
    float* __restrict__ as2, float* __restrict__ ad2, float* __restrict__ nf, int n) {
    __shared__ __align__(16) _Float16 bs[2 * 16 * 64 * 8];  // 32 KB
    __shared__ __align__(16) _Float16 as_[2 * 4 * 64 * 8];  // 8 KB
    __shared__ float nq[64][4];
    int t = threadIdx.x;
    int r0 = blockIdx.x * MBLK;
    // stage B = W2^T: thread t -> W2 row c=t (64 floats, 8 chunks)
    {
        int c = t;
        const float4* wrow = (const float4*)(W2 + (size_t)c * C_CH);
        int nt = c >> 4, cl = c & 15;
#pragma unroll
        for (int ch = 0; ch < 8; ++ch) {
            float4 f0 = wrow[ch * 2], f1 = wrow[ch * 2 + 1];
            int ks = ch >> 2, lg = ch & 3;
            _Float16* dst = &bs[(((ks * 16 + nt) * 64) + (lg * 16 + cl)) * 8];
            dst[0] = (_Float16)f0.x; dst[1] = (_Float16)f0.y;
            dst[2] = (_Float16)f0.z; dst[3] = (_Float16)f0.w;
            dst[4] = (_Float16)f1.x; dst[5] = (_Float16)f1.y;
            dst[6] = (_Float16)f1.z; dst[7] = (_Float16)f1.w;
        }
    }
    // stage A = BN(h1): row = t>>2, 2 chunks of 8 per thread
    {
        int row = t >> 2, q = t & 3;
        int rr = r0 + row;
        int mt = row >> 4, rl = row & 15;
        const float4* hrow = (const float4*)(h1 + (size_t)rr * C_CH);
#pragma unroll
        for (int cc = 0; cc < 2; ++cc) {
            int ch = q * 2 + cc;
            float4 f0 = make_float4(0, 0, 0, 0), f1 = make_float4(0, 0, 0, 0);
            if (rr < n) { f0 = hrow[ch * 2]; f1 = hrow[ch * 2 + 1]; }
            const float4 mu0 = *(const float4*)&mr[ch * 8];
            const float4 mu1 = *(const float4*)&mr[ch * 8 + 4];
            const float4 rs0 = *(const float4*)&mr[64 + ch * 8];
            const float4 rs1 = *(const float4*)&mr[64 + ch * 8 + 4];
            int ks = ch >> 2, lg = ch & 3;
            _Float16* dst = &as_[(((ks * 4 + mt) * 64) + (lg * 16 + rl)) * 8];
            dst[0] = (_Float16)((f0.x - mu0.x) * rs0.x);
            dst[1] = (_Float16)((f0.y - mu0.y) * rs0.y);
            dst[2] = (_Float16)((f0.z - mu0.z) * rs0.z);
            dst[3] = (_Float16)((f0.w - mu0.w) * rs0.w);
            dst[4] = (_Float16)((f1.x - mu1.x) * rs1.x);
            dst[5] = (_Float16)((f1.y - mu1.y) * rs1.y);
            dst[6] = (_Float16)((f1.z - mu1.z) * rs1.z);
            dst[7] = (_Float16)((f1.w - mu1.w) * rs1.w);
        }
    }
    __syncthreads();
    int w = t >> 6, l = t & 63;
    f32x4 acc[4][4];
#pragma unroll
    for (int mt = 0; mt < 4; ++mt)
#pragma unroll
        for (int nt = 0; nt < 4; ++nt) acc[mt][nt] = (f32x4){0.f, 0.f, 0.f, 0.f};
#pragma unroll
    for (int ks = 0; ks < 2; ++ks) {
        half8 af[4], bf[4];
#pragma unroll
        for (int mt = 0; mt < 4; ++mt)
            af[mt] = *(const half8*)&as_[(((ks * 4 + mt) * 64) + l) * 8];
#pragma unroll
        for (int nt = 0; nt < 4; ++nt)
            bf[nt] = *(const half8*)&bs[(((ks * 16 + (w * 4 + nt)) * 64) + l) * 8];
#pragma unroll
        for (int mt = 0; mt < 4; ++mt)
#pragma unroll
            for (int nt = 0; nt < 4; ++nt)
                acc[mt][nt] = __builtin_amdgcn_mfma_f32_16x16x32_f16(af[mt], bf[nt],
                                                                     acc[mt][nt], 0, 0, 0);
    }
    int cl = l & 15, rg = l >> 4;
    float atv_s[4], atv_d[4];
#pragma unroll
    for (int nt = 0; nt < 4; ++nt) {
        atv_s[nt] = att_s[w * 64 + nt * 16 + cl];
        atv_d[nt] = att_d[w * 64 + nt * 16 + cl];
    }
#pragma unroll
    for (int mt = 0; mt < 4; ++mt) {
#pragma unroll
        for (int r = 0; r < 4; ++r) {
            int rr = r0 + mt * 16 + rg * 4 + r;
            float vs = 0.f, vd = 0.f, vq = 0.f;
#pragma unroll
            for (int nt = 0; nt < 4; ++nt) {
                float v = acc[mt][nt][r];
                vs += atv_s[nt] * v;
                vd += atv_d[nt] * v;
                vq += v * v;
                if (rr < n)
                    x2h[(size_t)rr * C_HC + w * 64 + nt * 16 + cl] = __float2half(v);
            }
#pragma unroll
            for (int off = 1; off < 16; off <<= 1) {
                vs += __shfl_xor(vs, off);
                vd += __shfl_xor(vd, off);
                vq += __shfl_xor(vq, off);
            }
            if (cl == 0 && rr < n) {
                as2[rr * C_H + w] = vs;
                ad2[rr * C_H + w] = vd;
                nq[mt * 16 + rg * 4 + r][w] = vq;
            }
        }
    }
    __syncthreads();
    if (t < MBLK) {
        int rr = r0 + t;
        if (rr < n) {
            float qq = nq[t][0] + nq[t][1] + nq[t][2] + nq[t][3];
            nf[rr] = fmaxf(sqrtf(qq), 1e-8f);
        }
    }
}

// ---------------- node trust + struct norms ----------------
__global__ void k_trust(const float* __restrict__ sf, const float* __restrict__ Wt,
                        const float* __restrict__ bt, float* __restrict__ trust,
                        float* __restrict__ ns, int n) {
    int i = blockIdx.x * blockDim.x + threadIdx.x;
    if (i >= n) return;
    const float4* r4 = (const float4*)(sf + (size_t)i * C_S);
    const float4* w4 = (const float4*)Wt;
    float d = 0.f, q = 0.f;
#pragma unroll
    for (int k = 0; k < 8; ++k) {
        float4 a = r4[k], w = w4[k];
        d += a.x * w.x + a.y * w.y + a.z * w.z + a.w * w.w;
        q += a.x * a.x + a.y * a.y + a.z * a.z + a.w * a.w;
    }
    trust[i] = 1.f / (1.f + expf(-(d + bt[0])));
    ns[i] = fmaxf(sqrtf(q), 1e-8f);
}

// ---------------- per-edge gate logit ----------------
__global__ void k_gate(const int* __restrict__ srcs, const int* __restrict__ dsts,
                       const float* __restrict__ sf, const __half* __restrict__ x2h,
                       const float* __restrict__ ns, const float* __restrict__ nf,
                       const float* __restrict__ trust, const float* __restrict__ We1,
                       const float* __restrict__ be1, const float* __restrict__ We2,
                       const float* __restrict__ be2, const float* __restrict__ betas,
                       const int* __restrict__ slot, float* __restrict__ glog, int E) {
    __shared__ float sdL[EPB], fdL[EPB];
    int t = threadIdx.x;
    int w = t >> 6, l = t & 63;
    int g = l >> 4, q = l & 15;     // 16-lane group g, sublane q
    int e0 = blockIdx.x * EPB;
#pragma unroll
    for (int p = 0; p < 4; ++p) {
        int es = p * 16 + w * 4 + g;  // edge slot within block
        int e = e0 + es;
        float fd = 0.f, sd = 0.f;
        if (e < E) {
            int j = srcs[e], i = dsts[e];
            const __half2* aj = (const __half2*)(x2h + (size_t)j * C_HC + q * 16);
            const __half2* bi = (const __half2*)(x2h + (size_t)i * C_HC + q * 16);
            float4 ja = *(const float4*)aj;          // halves 0..7 of this lane's 16
            float4 jb = *(const float4*)(aj + 4);    // halves 8..15
            float4 ia = *(const float4*)bi;
            float4 ib = *(const float4*)(bi + 4);
            const __half2* pja = (const __half2*)&ja;
            const __half2* pjb = (const __half2*)&jb;
            const __half2* pia = (const __half2*)&ia;
            const __half2* pib = (const __half2*)&ib;
#pragma unroll
            for (int k = 0; k < 4; ++k) {
                float2 a = __half22float2(pja[k]), b = __half22float2(pia[k]);
                fd += a.x * b.x + a.y * b.y;
                float2 c = __half22float2(pjb[k]), d = __half22float2(pib[k]);
                fd += c.x * d.x + c.y * d.y;
            }
            float2 sj = *(const float2*)(sf + (size_t)j * C_S + q * 2);
            float2 si = *(const float2*)(sf + (size_t)i * C_S + q * 2);
            sd = sj.x * si.x + sj.y * si.y;
        }
#pragma unroll
        for (int off = 1; off < 16; off <<= 1) {
            fd += __shfl_xor(fd, off);
            sd += __shfl_xor(sd, off);
        }
        if (q == 0) { sdL[es] = sd; fdL[es] = fd; }
    }
    __syncthreads();
    if (t < EPB) {
        int e = e0 + t;
        if (e < E) {
            int j = srcs[e], i = dsts[e];
            float ss = sdL[t] / (ns[j] * ns[i]);
            float fs = fdL[t] / (nf[j] * nf[i]);
            float agr = ss * fs;
            float con = fabsf(ss - fs);
            float gate = be2[0];
#pragma unroll
            for (int o = 0; o < 8; ++o) {
                float hdn = We1[o * 4 + 0] * ss + We1[o * 4 + 1] * fs +
                            We1[o * 4 + 2] * agr + We1[o * 4 + 3] * con + be1[o];
                gate += We2[o] * fmaxf(hdn, 0.f);
            }
            float eb = (1.f / (1.f + expf(-gate))) * fmaxf(agr, 0.f);
            float et = sqrtf(fmaxf(trust[j] * trust[i], 0.f));
            float tb = et * fmaxf(0.5f * (ss + fs), 0.f);
            glog[slot[e]] = betas[0] * ss + betas[1] * fs + betas[2] * agr +
                            betas[3] * eb + betas[4] * tb;
        }
    }
}

// ---------------- layer 2 aggregation: 128 threads / node, LDS-cached alpha ----------------
__global__ void k_layer2(const int* __restrict__ row_ptr, const int* __restrict__ adj_src,
                         const __half* __restrict__ x2h, const float* __restrict__ as2,
                         const float* __restrict__ ad2, const float* __restrict__ glog,
                         const float* __restrict__ bias2, float* __restrict__ out) {
    int d = blockIdx.x;
    int t = threadIdx.x, hh = t >> 5, cp = t & 31;
    int beg = row_ptr[d], end = row_ptr[d + 1];
    float adh = ad2[d * C_H + hh];
    float m = -1e30f;
    for (int e = beg + cp; e < end; e += 32)
        m = fmaxf(m, lrelu(as2[adj_src[e] * C_H + hh] + adh) + glog[e]);
    m = sub_max32(m);
    float sum = 0.f;
    for (int e = beg + cp; e < end; e += 32)
        sum += expf(lrelu(as2[adj_src[e] * C_H + hh] + adh) + glog[e] - m);
    sum = sub_sum32(sum);
    float inv = 1.f / (sum + 1e-16f);
    __shared__ float alpha_l[C_H][ACH];
    __shared__ int src_l[ACH];
    float accx = 0.f, accy = 0.f;
    for (int cbeg = beg; cbeg < end; cbeg += ACH) {
        int cn = min(end - cbeg, ACH);
        __syncthreads();
        if (cp < cn) {
            int s = adj_src[cbeg + cp];
            if (hh == 0) src_l[cp] = s;
            alpha_l[hh][cp] =
                expf(lrelu(as2[s * C_H + hh] + adh) + glog[cbeg + cp] - m) * inv;
        }
        __syncthreads();
        for (int i = 0; i < cn; ++i) {
            int s = src_l[i];
            float a = alpha_l[hh][i];
            float2 v = __half22float2(
                *(const __half2*)(x2h + (size_t)s * C_HC + hh * 64 + cp * 2));
            accx += a * v.x;
            accy += a * v.y;
        }
    }
    __shared__ float2 red[128];
    red[t] = make_float2(accx, accy);
    __syncthreads();
    if (t < 32) {
        float2 r0 = red[t], r1 = red[t + 32], r2 = red[t + 64], r3 = red[t + 96];
        float2 b = *(const float2*)&bias2[t * 2];
        float vx = (r0.x + r1.x + r2.x + r3.x) * 0.25f + b.x;
        float vy = (r0.y + r1.y + r2.y + r3.y) * 0.25f + b.y;
        *(float2*)&out[(size_t)d * C_CH + t * 2] = make_float2(vx, vy);
    }
}

static inline size_t al256(size_t x) { return (x + 255) & ~(size_t)255; }

extern "C" void kernel_launch(void* const* d_in, const int* in_sizes, int n_in,
                              void* d_out, int out_size, void* d_ws, size_t ws_size,
                              hipStream_t stream) {
    const float* x      = (const float*)d_in[0];
    const int*   ei     = (const int*)d_in[1];
    const float* sf     = (const float*)d_in[2];
    const float* W1     = (const float*)d_in[3];
    const float* atts1  = (const float*)d_in[4];
    const float* attd1  = (const float*)d_in[5];
    const float* bias1  = (const float*)d_in[6];
    const float* W2     = (const float*)d_in[7];
    const float* atts2  = (const float*)d_in[8];
    const float* attd2  = (const float*)d_in[9];
    const float* bias2  = (const float*)d_in[10];
    const float* Wt     = (const float*)d_in[11];
    const float* bt     = (const float*)d_in[12];
    const float* We1    = (const float*)d_in[13];
    const float* be1    = (const float*)d_in[14];
    const float* We2    = (const float*)d_in[15];
    const float* be2    = (const float*)d_in[16];
    const float* betas  = (const float*)d_in[17];

    const int N = in_sizes[0] / C_DIN;
    const int E = in_sizes[1] / 2;
    const int* srcs = ei;
    const int* dsts = ei + E;

    // workspace carve-up; disjoint-lifetime aliases: x2h reuses hhlf,
    // as2/ad2 reuse a_s1/a_d1
    char* p = (char*)d_ws;
    size_t off = 0;
    auto take = [&](size_t bytes) { char* r = p + off; off = al256(off + bytes); return r; };
    __half* hhlf  = (__half*)take((size_t)N * C_HC * 2);  // layer-1 h (fp16); reused as x2h
    float* h1     = (float*)take((size_t)N * C_CH * 4);
    float* a_s1   = (float*)take((size_t)N * C_H * 4);    // reused as as2
    float* a_d1   = (float*)take((size_t)N * C_H * 4);    // reused as ad2
    float* nf     = (float*)take((size_t)N * 4);
    float* ns     = (float*)take((size_t)N * 4);
    float* trust  = (float*)take((size_t)N * 4);
    float* glog   = (float*)take((size_t)E * 4);          // CSR-ordered
    int*   deg    = (int*)take((size_t)N * 4);
    int*   rowp   = (int*)take((size_t)(N + 1) * 4);
    int*   cursor = (int*)take((size_t)N * 4);
    int*   adj_s  = (int*)take((size_t)E * 4);
    int*   slot   = (int*)take((size_t)E * 4);
    float* bn     = (float*)take(256 * 4);  // [0:64) sum, [64:128) sumsq, [128:256) mu/rstd
    (void)ws_size;
    __half* x2h = hhlf;   // alias: hhlf dead after k_layer1, x2h born in k_gemm2
    float* as2  = a_s1;   // alias: a_s1 dead after k_layer1
    float* ad2  = a_d1;   // alias: a_d1 dead after k_layer1

    hipMemsetAsync(deg, 0, (size_t)N * 4, stream);
    hipMemsetAsync(bn, 0, 128 * 4, stream);

    // CSR build
    k_count<<<(E + 255) / 256, 256, 0, stream>>>(dsts, deg, E);
    k_scan<<<1, 1024, 0, stream>>>(deg, rowp, cursor, N);
    k_scatter<<<(E + 255) / 256, 256, 0, stream>>>(srcs, dsts, cursor, adj_s, slot, E);

    // layer 1
    k_gemm1<<<(N + MBLK - 1) / MBLK, 256, 0, stream>>>(x, W1, atts1, attd1, hhlf, a_s1, a_d1, N);
    k_layer1<<<N, 128, 0, stream>>>(rowp, adj_s, hhlf, a_s1, a_d1, bias1, h1);
    k_bnstats<<<128, 256, 0, stream>>>(h1, bn, N);
    k_bnfinal<<<1, 64, 0, stream>>>(bn, bn + 128, N);

    // layer 2
    k_gemm2<<<(N + MBLK - 1) / MBLK, 256, 0, stream>>>(h1, W2, atts2, attd2, bn + 128, x2h,
                                                       as2, ad2, nf, N);
    k_trust<<<(N + 255) / 256, 256, 0, stream>>>(sf, Wt, bt, trust, ns, N);
    k_gate<<<(E + EPB - 1) / EPB, 256, 0, stream>>>(srcs, dsts, sf, x2h, ns, nf, trust,
                                                    We1, be1, We2, be2, betas, slot, glog, E);
    k_layer2<<<N, 128, 0, stream>>>(rowp, adj_s, x2h, as2, ad2, glog, bias2, (float*)d_out);
}

// Round 9
// 316.603 us; speedup vs baseline: 1.8277x; 1.0633x over previous
//
#include <hip/hip_runtime.h>
#include <hip/hip_bf16.h>
#include <hip/hip_fp16.h>

// Problem constants (verified against setup_inputs)
#define C_DIN 128
#define C_H 4
#define C_CH 64     // per-head channels (CHID == COUT == 64)
#define C_HC 256    // H * CH
#define C_S 32
#define EPB 64      // edges per block in k_gate
#define ACH 32      // aggregation chunk (edges) cached in LDS
#define MBLK 64     // GEMM M-tile (rows per block)

typedef __attribute__((ext_vector_type(8))) _Float16 half8;
typedef __attribute__((ext_vector_type(4))) float f32x4;

__device__ __forceinline__ float lrelu(float x) { return x >= 0.f ? x : 0.2f * x; }

// reductions confined to 32-lane subgroup (offsets <=16 never cross halves)
__device__ __forceinline__ float sub_sum32(float v) {
#pragma unroll
    for (int off = 16; off > 0; off >>= 1) v += __shfl_xor(v, off);
    return v;
}
__device__ __forceinline__ float sub_max32(float v) {
#pragma unroll
    for (int off = 16; off > 0; off >>= 1) v = fmaxf(v, __shfl_xor(v, off));
    return v;
}

// ---------------- CSR build ----------------
__global__ void k_count(const int* __restrict__ dst, int* __restrict__ deg, int E) {
    int e = blockIdx.x * blockDim.x + threadIdx.x;
    if (e < E) atomicAdd(&deg[dst[e]], 1);
}

__global__ void k_scan(const int* __restrict__ deg, int* __restrict__ row_ptr,
                       int* __restrict__ cursor, int n) {
    __shared__ int part[1024];
    int t = threadIdx.x;
    const int C = (n + 1023) / 1024;
    int base = t * C;
    int s = 0;
    for (int k = 0; k < C; ++k) {
        int idx = base + k;
        if (idx < n) s += deg[idx];
    }
    part[t] = s;
    __syncthreads();
    for (int off = 1; off < 1024; off <<= 1) {
        int v = (t >= off) ? part[t - off] : 0;
        __syncthreads();
        part[t] += v;
        __syncthreads();
    }
    int run = (t == 0) ? 0 : part[t - 1];
    for (int k = 0; k < C; ++k) {
        int idx = base + k;
        if (idx < n) { row_ptr[idx] = run; cursor[idx] = run; run += deg[idx]; }
    }
    if (t == 1023) row_ptr[n] = run;
}

// scatter: CSR-ordered adjacency (src + dst per slot) so k_gate can run in
// CSR order (dst-side rows become cache hits) and write glog linearly.
__global__ void k_scatter(const int* __restrict__ src, const int* __restrict__ dst,
                          int* __restrict__ cursor, int* __restrict__ adj_src,
                          int* __restrict__ adj_dst, int E) {
    int e = blockIdx.x * blockDim.x + threadIdx.x;
    if (e < E) {
        int d = dst[e];
        int p = atomicAdd(&cursor[d], 1);
        adj_src[p] = src[e];
        adj_dst[p] = d;
    }
}

// ---------------- layer 1 GEMM (MFMA fp16): h = x @ W1^T, fused a_s1/a_d1 ----------------
// 4 waves/block; wave w owns cols [w*64, w*64+64) == head w. M_BLK=64 rows.
__global__ __launch_bounds__(256) void k_gemm1(
    const float* __restrict__ x, const float* __restrict__ W1,
    const float* __restrict__ att_s, const float* __restrict__ att_d,
    __half* __restrict__ hh_out, float* __restrict__ a_s, float* __restrict__ a_d, int n) {
    __shared__ __align__(16) _Float16 bs[4 * 16 * 64 * 8];  // [ks][ntg][lane][8] = 64 KB
    __shared__ __align__(16) _Float16 as_[4 * 4 * 64 * 8];  // [ks][mt][lane][8]  = 16 KB
    int t = threadIdx.x;
    int r0 = blockIdx.x * MBLK;
    {
        int c = t;
        const float4* wrow = (const float4*)(W1 + (size_t)c * C_DIN);
        int nt = c >> 4, cl = c & 15;
#pragma unroll
        for (int ch = 0; ch < 16; ++ch) {
            float4 f0 = wrow[ch * 2], f1 = wrow[ch * 2 + 1];
            int ks = ch >> 2, lg = ch & 3;
            _Float16* dst = &bs[(((ks * 16 + nt) * 64) + (lg * 16 + cl)) * 8];
            dst[0] = (_Float16)f0.x; dst[1] = (_Float16)f0.y;
            dst[2] = (_Float16)f0.z; dst[3] = (_Float16)f0.w;
            dst[4] = (_Float16)f1.x; dst[5] = (_Float16)f1.y;
            dst[6] = (_Float16)f1.z; dst[7] = (_Float16)f1.w;
        }
    }
    {
        int row = t >> 2, q = t & 3;
        int rr = r0 + row;
        int mt = row >> 4, rl = row & 15;
        const float4* xrow = (const float4*)(x + (size_t)rr * C_DIN);
#pragma unroll
        for (int cc = 0; cc < 4; ++cc) {
            int ch = q * 4 + cc;
            float4 f0 = make_float4(0, 0, 0, 0), f1 = make_float4(0, 0, 0, 0);
            if (rr < n) { f0 = xrow[ch * 2]; f1 = xrow[ch * 2 + 1]; }
            int ks = ch >> 2, lg = ch & 3;
            _Float16* dst = &as_[(((ks * 4 + mt) * 64) + (lg * 16 + rl)) * 8];
            dst[0] = (_Float16)f0.x; dst[1] = (_Float16)f0.y;
            dst[2] = (_Float16)f0.z; dst[3] = (_Float16)f0.w;
            dst[4] = (_Float16)f1.x; dst[5] = (_Float16)f1.y;
            dst[6] = (_Float16)f1.z; dst[7] = (_Float16)f1.w;
        }
    }
    __syncthreads();
    int w = t >> 6, l = t & 63;
    f32x4 acc[4][4];
#pragma unroll
    for (int mt = 0; mt < 4; ++mt)
#pragma unroll
        for (int nt = 0; nt < 4; ++nt) acc[mt][nt] = (f32x4){0.f, 0.f, 0.f, 0.f};
#pragma unroll
    for (int ks = 0; ks < 4; ++ks) {
        half8 af[4], bf[4];
#pragma unroll
        for (int mt = 0; mt < 4; ++mt)
            af[mt] = *(const half8*)&as_[(((ks * 4 + mt) * 64) + l) * 8];
#pragma unroll
        for (int nt = 0; nt < 4; ++nt)
            bf[nt] = *(const half8*)&bs[(((ks * 16 + (w * 4 + nt)) * 64) + l) * 8];
#pragma unroll
        for (int mt = 0; mt < 4; ++mt)
#pragma unroll
            for (int nt = 0; nt < 4; ++nt)
                acc[mt][nt] = __builtin_amdgcn_mfma_f32_16x16x32_f16(af[mt], bf[nt],
                                                                     acc[mt][nt], 0, 0, 0);
    }
    int cl = l & 15, rg = l >> 4;
    float atv_s[4], atv_d[4];
#pragma unroll
    for (int nt = 0; nt < 4; ++nt) {
        atv_s[nt] = att_s[w * 64 + nt * 16 + cl];
        atv_d[nt] = att_d[w * 64 + nt * 16 + cl];
    }
#pragma unroll
    for (int mt = 0; mt < 4; ++mt) {
#pragma unroll
        for (int r = 0; r < 4; ++r) {
            int rr = r0 + mt * 16 + rg * 4 + r;
            float vs = 0.f, vd = 0.f;
#pragma unroll
            for (int nt = 0; nt < 4; ++nt) {
                float v = acc[mt][nt][r];
                vs += atv_s[nt] * v;
                vd += atv_d[nt] * v;
                if (rr < n)
                    hh_out[(size_t)rr * C_HC + w * 64 + nt * 16 + cl] = __float2half(v);
            }
#pragma unroll
            for (int off = 1; off < 16; off <<= 1) {
                vs += __shfl_xor(vs, off);
                vd += __shfl_xor(vd, off);
            }
            if (cl == 0 && rr < n) { a_s[rr * C_H + w] = vs; a_d[rr * C_H + w] = vd; }
        }
    }
}

// ---------------- layer 1 aggregation: 128 threads / node, LDS-cached alpha ----------------
__global__ void k_layer1(const int* __restrict__ row_ptr, const int* __restrict__ adj_src,
                         const __half* __restrict__ hhlf, const float* __restrict__ a_s,
                         const float* __restrict__ a_d, const float* __restrict__ bias1,
                         float* __restrict__ h1) {
    int d = blockIdx.x;
    int t = threadIdx.x, hh = t >> 5, cp = t & 31;
    int beg = row_ptr[d], end = row_ptr[d + 1];
    float adh = a_d[d * C_H + hh];
    float self = lrelu(a_s[d * C_H + hh] + adh);
    float m = self;
    for (int e = beg + cp; e < end; e += 32)
        m = fmaxf(m, lrelu(a_s[adj_src[e] * C_H + hh] + adh));
    m = sub_max32(m);
    float sum = (cp == 0) ? expf(self - m) : 0.f;
    for (int e = beg + cp; e < end; e += 32)
        sum += expf(lrelu(a_s[adj_src[e] * C_H + hh] + adh) - m);
    sum = sub_sum32(sum);
    float inv = 1.f / (sum + 1e-16f);
    __shared__ float alpha_l[C_H][ACH];
    __shared__ int src_l[ACH];
    const __half2* selfrow = (const __half2*)(hhlf + (size_t)d * C_HC + hh * 64);
    float sa = expf(self - m) * inv;
    float2 sv = __half22float2(selfrow[cp]);
    float accx = sa * sv.x, accy = sa * sv.y;
    for (int cbeg = beg; cbeg < end; cbeg += ACH) {
        int cn = min(end - cbeg, ACH);
        __syncthreads();
        if (cp < cn) {
            int s = adj_src[cbeg + cp];
            if (hh == 0) src_l[cp] = s;
            alpha_l[hh][cp] = expf(lrelu(a_s[s * C_H + hh] + adh) - m) * inv;
        }
        __syncthreads();
        for (int i = 0; i < cn; ++i) {
            int s = src_l[i];
            float a = alpha_l[hh][i];
            float2 v = __half22float2(
                *(const __half2*)(hhlf + (size_t)s * C_HC + hh * 64 + cp * 2));
            accx += a * v.x;
            accy += a * v.y;
        }
    }
    __shared__ float2 red[128];
    red[t] = make_float2(accx, accy);
    __syncthreads();
    if (t < 32) {
        float2 r0 = red[t], r1 = red[t + 32], r2 = red[t + 64], r3 = red[t + 96];
        float2 b = *(const float2*)&bias1[t * 2];
        float vx = (r0.x + r1.x + r2.x + r3.x) * 0.25f + b.x;
        float vy = (r0.y + r1.y + r2.y + r3.y) * 0.25f + b.y;
        *(float2*)&h1[(size_t)d * C_CH + t * 2] =
            make_float2(fmaxf(vx, 0.f), fmaxf(vy, 0.f));
    }
}

// ---------------- batch-norm stats ----------------
__global__ void k_bnstats(const float* __restrict__ h1, float* __restrict__ bn, int n) {
    int t = threadIdx.x;
    int c = t & 63, rg = t >> 6;
    float s = 0.f, s2 = 0.f;
    for (int r = blockIdx.x * 4 + rg; r < n; r += gridDim.x * 4) {
        float v = h1[(size_t)r * C_CH + c];
        s += v;
        s2 += v * v;
    }
    __shared__ float ls[256], ls2[256];
    ls[t] = s; ls2[t] = s2;
    __syncthreads();
    if (t < 64) {
        s = ls[t] + ls[t + 64] + ls[t + 128] + ls[t + 192];
        s2 = ls2[t] + ls2[t + 64] + ls2[t + 128] + ls2[t + 192];
        atomicAdd(&bn[c], s);
        atomicAdd(&bn[64 + c], s2);
    }
}

__global__ void k_bnfinal(const float* __restrict__ bn, float* __restrict__ mr, int n) {
    int c = threadIdx.x;
    if (c < 64) {
        float mu = bn[c] / n;
        float var = bn[64 + c] / n - mu * mu;
        mr[c] = mu;
        mr[64 + c] = rsqrtf(var + 1e-5f);
    }
}

// ---------------- layer 2 GEMM (MFMA fp16): x2 = BN(h1) @ W2^T, fused as2/ad2/nf ----------
__global__ __launch_bounds__(256) void k_gemm2(
    const float* __restrict__ h1, const float* __restrict__ W2,
    const float* __restrict__ att_s, const float* __restrict__ att_d,
    const float* __restrict__ mr, __half* __restrict__ x2h,
    float* __restrict__ as2, float* __restrict__ ad2, float* __restrict__ nf, int n) {
    __shared__ __align__(16) _Float16 bs[2 * 16 * 64 * 8];  // 32 KB
    __shared__ __align__(16) _Float16 as_[2 * 4 * 64 * 8];  // 8 KB
    __shared__ float nq[64][4];
    int t = threadIdx.x;
    int r0 = blockIdx.x * MBLK;
    {
        int c = t;
        const float4* wrow = (const float4*)(W2 + (size_t)c * C_CH);
        int nt = c >> 4, cl = c & 15;
#pragma unroll
        for (int ch = 0; ch < 8; ++ch) {
            float4 f0 = wrow[ch * 2], f1 = wrow[ch * 2 + 1];
            int ks = ch >> 2, lg = ch & 3;
            _Float16* dst = &bs[(((ks * 16 + nt) * 64) + (lg * 16 + cl)) * 8];
            dst[0] = (_Float16)f0.x; dst[1] = (_Float16)f0.y;
            dst[2] = (_Float16)f0.z; dst[3] = (_Float16)f0.w;
            dst[4] = (_Float16)f1.x; dst[5] = (_Float16)f1.y;
            dst[6] = (_Float16)f1.z; dst[7] = (_Float16)f1.w;
        }
    }
    {
        int row = t >> 2, q = t & 3;
        int rr = r0 + row;
        int mt = row >> 4, rl = row & 15;
        const float4* hrow = (const float4*)(h1 + (size_t)rr * C_CH);
#pragma unroll
        for (int cc = 0; cc < 2; ++cc) {
            int ch = q * 2 + cc;
            float4 f0 = make_float4(0, 0, 0, 0), f1 = make_float4(0, 0, 0, 0);
            if (rr < n) { f0 = hrow[ch * 2]; f1 = hrow[ch * 2 + 1]; }
            const float4 mu0 = *(const float4*)&mr[ch * 8];
            const float4 mu1 = *(const float4*)&mr[ch * 8 + 4];
            const float4 rs0 = *(const float4*)&mr[64 + ch * 8];
            const float4 rs1 = *(const float4*)&mr[64 + ch * 8 + 4];
            int ks = ch >> 2, lg = ch & 3;
            _Float16* dst = &as_[(((ks * 4 + mt) * 64) + (lg * 16 + rl)) * 8];
            dst[0] = (_Float16)((f0.x - mu0.x) * rs0.x);
            dst[1] = (_Float16)((f0.y - mu0.y) * rs0.y);
            dst[2] = (_Float16)((f0.z - mu0.z) * rs0.z);
            dst[3] = (_Float16)((f0.w - mu0.w) * rs0.w);
            dst[4] = (_Float16)((f1.x - mu1.x) * rs1.x);
            dst[5] = (_Float16)((f1.y - mu1.y) * rs1.y);
            dst[6] = (_Float16)((f1.z - mu1.z) * rs1.z);
            dst[7] = (_Float16)((f1.w - mu1.w) * rs1.w);
        }
    }
    __syncthreads();
    int w = t >> 6, l = t & 63;
    f32x4 acc[4][4];
#pragma unroll
    for (int mt = 0; mt < 4; ++mt)
#pragma unroll
        for (int nt = 0; nt < 4; ++nt) acc[mt][nt] = (f32x4){0.f, 0.f, 0.f, 0.f};
#pragma unroll
    for (int ks = 0; ks < 2; ++ks) {
        half8 af[4], bf[4];
#pragma unroll
        for (int mt = 0; mt < 4; ++mt)
            af[mt] = *(const half8*)&as_[(((ks * 4 + mt) * 64) + l) * 8];
#pragma unroll
        for (int nt = 0; nt < 4; ++nt)
            bf[nt] = *(const half8*)&bs[(((ks * 16 + (w * 4 + nt)) * 64) + l) * 8];
#pragma unroll
        for (int mt = 0; mt < 4; ++mt)
#pragma unroll
            for (int nt = 0; nt < 4; ++nt)
                acc[mt][nt] = __builtin_amdgcn_mfma_f32_16x16x32_f16(af[mt], bf[nt],
                                                                     acc[mt][nt], 0, 0, 0);
    }
    int cl = l & 15, rg = l >> 4;
    float atv_s[4], atv_d[4];
#pragma unroll
    for (int nt = 0; nt < 4; ++nt) {
        atv_s[nt] = att_s[w * 64 + nt * 16 + cl];
        atv_d[nt] = att_d[w * 64 + nt * 16 + cl];
    }
#pragma unroll
    for (int mt = 0; mt < 4; ++mt) {
#pragma unroll
        for (int r = 0; r < 4; ++r) {
            int rr = r0 + mt * 16 + rg * 4 + r;
            float vs = 0.f, vd = 0.f, vq = 0.f;
#pragma unroll
            for (int nt = 0; nt < 4; ++nt) {
                float v = acc[mt][nt][r];
                vs += atv_s[nt] * v;
                vd += atv_d[nt] * v;
                vq += v * v;
                if (rr < n)
                    x2h[(size_t)rr * C_HC + w * 64 + nt * 16 + cl] = __float2half(v);
            }
#pragma unroll
            for (int off = 1; off < 16; off <<= 1) {
                vs += __shfl_xor(vs, off);
                vd += __shfl_xor(vd, off);
                vq += __shfl_xor(vq, off);
            }
            if (cl == 0 && rr < n) {
                as2[rr * C_H + w] = vs;
                ad2[rr * C_H + w] = vd;
                nq[mt * 16 + rg * 4 + r][w] = vq;
            }
        }
    }
    __syncthreads();
    if (t < MBLK) {
        int rr = r0 + t;
        if (rr < n) {
            float qq = nq[t][0] + nq[t][1] + nq[t][2] + nq[t][3];
            nf[rr] = fmaxf(sqrtf(qq), 1e-8f);
        }
    }
}

// ---------------- node trust + struct norms ----------------
__global__ void k_trust(const float* __restrict__ sf, const float* __restrict__ Wt,
                        const float* __restrict__ bt, float* __restrict__ trust,
                        float* __restrict__ ns, int n) {
    int i = blockIdx.x * blockDim.x + threadIdx.x;
    if (i >= n) return;
    const float4* r4 = (const float4*)(sf + (size_t)i * C_S);
    const float4* w4 = (const float4*)Wt;
    float d = 0.f, q = 0.f;
#pragma unroll
    for (int k = 0; k < 8; ++k) {
        float4 a = r4[k], w = w4[k];
        d += a.x * w.x + a.y * w.y + a.z * w.z + a.w * w.w;
        q += a.x * a.x + a.y * a.y + a.z * a.z + a.w * a.w;
    }
    trust[i] = 1.f / (1.f + expf(-(d + bt[0])));
    ns[i] = fmaxf(sqrtf(q), 1e-8f);
}

// ---------------- per-edge gate logit (CSR order: dst-side reads cache-hit) -------------
__global__ void k_gate(const int* __restrict__ adj_src, const int* __restrict__ adj_dst,
                       const float* __restrict__ sf, const __half* __restrict__ x2h,
                       const float* __restrict__ ns, const float* __restrict__ nf,
                       const float* __restrict__ trust, const float* __restrict__ We1,
                       const float* __restrict__ be1, const float* __restrict__ We2,
                       const float* __restrict__ be2, const float* __restrict__ betas,
                       float* __restrict__ glog, int E) {
    __shared__ float sdL[EPB], fdL[EPB];
    int t = threadIdx.x;
    int w = t >> 6, l = t & 63;
    int g = l >> 4, q = l & 15;     // 16-lane group g, sublane q
    int e0 = blockIdx.x * EPB;
#pragma unroll
    for (int p = 0; p < 4; ++p) {
        int es = p * 16 + w * 4 + g;  // edge slot within block
        int e = e0 + es;
        float fd = 0.f, sd = 0.f;
        if (e < E) {
            int j = adj_src[e], i = adj_dst[e];
            const __half2* aj = (const __half2*)(x2h + (size_t)j * C_HC + q * 16);
            const __half2* bi = (const __half2*)(x2h + (size_t)i * C_HC + q * 16);
            float4 ja = *(const float4*)aj;          // halves 0..7 of this lane's 16
            float4 jb = *(const float4*)(aj + 4);    // halves 8..15
            float4 ia = *(const float4*)bi;
            float4 ib = *(const float4*)(bi + 4);
            const __half2* pja = (const __half2*)&ja;
            const __half2* pjb = (const __half2*)&jb;
            const __half2* pia = (const __half2*)&ia;
            const __half2* pib = (const __half2*)&ib;
#pragma unroll
            for (int k = 0; k < 4; ++k) {
                float2 a = __half22float2(pja[k]), b = __half22float2(pia[k]);
                fd += a.x * b.x + a.y * b.y;
                float2 c = __half22float2(pjb[k]), d = __half22float2(pib[k]);
                fd += c.x * d.x + c.y * d.y;
            }
            float2 sj = *(const float2*)(sf + (size_t)j * C_S + q * 2);
            float2 si = *(const float2*)(sf + (size_t)i * C_S + q * 2);
            sd = sj.x * si.x + sj.y * si.y;
        }
#pragma unroll
        for (int off = 1; off < 16; off <<= 1) {
            fd += __shfl_xor(fd, off);
            sd += __shfl_xor(sd, off);
        }
        if (q == 0) { sdL[es] = sd; fdL[es] = fd; }
    }
    __syncthreads();
    if (t < EPB) {
        int e = e0 + t;
        if (e < E) {
            int j = adj_src[e], i = adj_dst[e];
            float ss = sdL[t] / (ns[j] * ns[i]);
            float fs = fdL[t] / (nf[j] * nf[i]);
            float agr = ss * fs;
            float con = fabsf(ss - fs);
            float gate = be2[0];
#pragma unroll
            for (int o = 0; o < 8; ++o) {
                float hdn = We1[o * 4 + 0] * ss + We1[o * 4 + 1] * fs +
                            We1[o * 4 + 2] * agr + We1[o * 4 + 3] * con + be1[o];
                gate += We2[o] * fmaxf(hdn, 0.f);
            }
            float eb = (1.f / (1.f + expf(-gate))) * fmaxf(agr, 0.f);
            float et = sqrtf(fmaxf(trust[j] * trust[i], 0.f));
            float tb = et * fmaxf(0.5f * (ss + fs), 0.f);
            glog[e] = betas[0] * ss + betas[1] * fs + betas[2] * agr +
                      betas[3] * eb + betas[4] * tb;
        }
    }
}

// ---------------- layer 2 aggregation: 128 threads / node, LDS-cached alpha ----------------
__global__ void k_layer2(const int* __restrict__ row_ptr, const int* __restrict__ adj_src,
                         const __half* __restrict__ x2h, const float* __restrict__ as2,
                         const float* __restrict__ ad2, const float* __restrict__ glog,
                         const float* __restrict__ bias2, float* __restrict__ out) {
    int d = blockIdx.x;
    int t = threadIdx.x, hh = t >> 5, cp = t & 31;
    int beg = row_ptr[d], end = row_ptr[d + 1];
    float adh = ad2[d * C_H + hh];
    float m = -1e30f;
    for (int e = beg + cp; e < end; e += 32)
        m = fmaxf(m, lrelu(as2[adj_src[e] * C_H + hh] + adh) + glog[e]);
    m = sub_max32(m);
    float sum = 0.f;
    for (int e = beg + cp; e < end; e += 32)
        sum += expf(lrelu(as2[adj_src[e] * C_H + hh] + adh) + glog[e] - m);
    sum = sub_sum32(sum);
    float inv = 1.f / (sum + 1e-16f);
    __shared__ float alpha_l[C_H][ACH];
    __shared__ int src_l[ACH];
    float accx = 0.f, accy = 0.f;
    for (int cbeg = beg; cbeg < end; cbeg += ACH) {
        int cn = min(end - cbeg, ACH);
        __syncthreads();
        if (cp < cn) {
            int s = adj_src[cbeg + cp];
            if (hh == 0) src_l[cp] = s;
            alpha_l[hh][cp] =
                expf(lrelu(as2[s * C_H + hh] + adh) + glog[cbeg + cp] - m) * inv;
        }
        __syncthreads();
        for (int i = 0; i < cn; ++i) {
            int s = src_l[i];
            float a = alpha_l[hh][i];
            float2 v = __half22float2(
                *(const __half2*)(x2h + (size_t)s * C_HC + hh * 64 + cp * 2));
            accx += a * v.x;
            accy += a * v.y;
        }
    }
    __shared__ float2 red[128];
    red[t] = make_float2(accx, accy);
    __syncthreads();
    if (t < 32) {
        float2 r0 = red[t], r1 = red[t + 32], r2 = red[t + 64], r3 = red[t + 96];
        float2 b = *(const float2*)&bias2[t * 2];
        float vx = (r0.x + r1.x + r2.x + r3.x) * 0.25f + b.x;
        float vy = (r0.y + r1.y + r2.y + r3.y) * 0.25f + b.y;
        *(float2*)&out[(size_t)d * C_CH + t * 2] = make_float2(vx, vy);
    }
}

static inline size_t al256(size_t x) { return (x + 255) & ~(size_t)255; }

extern "C" void kernel_launch(void* const* d_in, const int* in_sizes, int n_in,
                              void* d_out, int out_size, void* d_ws, size_t ws_size,
                              hipStream_t stream) {
    const float* x      = (const float*)d_in[0];
    const int*   ei     = (const int*)d_in[1];
    const float* sf     = (const float*)d_in[2];
    const float* W1     = (const float*)d_in[3];
    const float* atts1  = (const float*)d_in[4];
    const float* attd1  = (const float*)d_in[5];
    const float* bias1  = (const float*)d_in[6];
    const float* W2     = (const float*)d_in[7];
    const float* atts2  = (const float*)d_in[8];
    const float* attd2  = (const float*)d_in[9];
    const float* bias2  = (const float*)d_in[10];
    const float* Wt     = (const float*)d_in[11];
    const float* bt     = (const float*)d_in[12];
    const float* We1    = (const float*)d_in[13];
    const float* be1    = (const float*)d_in[14];
    const float* We2    = (const float*)d_in[15];
    const float* be2    = (const float*)d_in[16];
    const float* betas  = (const float*)d_in[17];

    const int N = in_sizes[0] / C_DIN;
    const int E = in_sizes[1] / 2;
    const int* srcs = ei;
    const int* dsts = ei + E;

    // workspace carve-up; disjoint-lifetime aliases: x2h reuses hhlf,
    // as2/ad2 reuse a_s1/a_d1
    char* p = (char*)d_ws;
    size_t off = 0;
    auto take = [&](size_t bytes) { char* r = p + off; off = al256(off + bytes); return r; };
    __half* hhlf  = (__half*)take((size_t)N * C_HC * 2);  // layer-1 h (fp16); reused as x2h
    float* h1     = (float*)take((size_t)N * C_CH * 4);
    float* a_s1   = (float*)take((size_t)N * C_H * 4);    // reused as as2
    float* a_d1   = (float*)take((size_t)N * C_H * 4);    // reused as ad2
    float* nf     = (float*)take((size_t)N * 4);
    float* ns     = (float*)take((size_t)N * 4);
    float* trust  = (float*)take((size_t)N * 4);
    float* glog   = (float*)take((size_t)E * 4);          // CSR-ordered
    int*   deg    = (int*)take((size_t)N * 4);
    int*   rowp   = (int*)take((size_t)(N + 1) * 4);
    int*   cursor = (int*)take((size_t)N * 4);
    int*   adj_s  = (int*)take((size_t)E * 4);
    int*   adj_d  = (int*)take((size_t)E * 4);
    float* bn     = (float*)take(256 * 4);  // [0:64) sum, [64:128) sumsq, [128:256) mu/rstd
    (void)ws_size;
    __half* x2h = hhlf;   // alias: hhlf dead after k_layer1, x2h born in k_gemm2
    float* as2  = a_s1;   // alias: a_s1 dead after k_layer1
    float* ad2  = a_d1;   // alias: a_d1 dead after k_layer1

    hipMemsetAsync(deg, 0, (size_t)N * 4, stream);
    hipMemsetAsync(bn, 0, 128 * 4, stream);

    // CSR build
    k_count<<<(E + 255) / 256, 256, 0, stream>>>(dsts, deg, E);
    k_scan<<<1, 1024, 0, stream>>>(deg, rowp, cursor, N);
    k_scatter<<<(E + 255) / 256, 256, 0, stream>>>(srcs, dsts, cursor, adj_s, adj_d, E);

    // layer 1
    k_gemm1<<<(N + MBLK - 1) / MBLK, 256, 0, stream>>>(x, W1, atts1, attd1, hhlf, a_s1, a_d1, N);
    k_layer1<<<N, 128, 0, stream>>>(rowp, adj_s, hhlf, a_s1, a_d1, bias1, h1);
    k_bnstats<<<128, 256, 0, stream>>>(h1, bn, N);
    k_bnfinal<<<1, 64, 0, stream>>>(bn, bn + 128, N);

    // layer 2
    k_gemm2<<<(N + MBLK - 1) / MBLK, 256, 0, stream>>>(h1, W2, atts2, attd2, bn + 128, x2h,
                                                       as2, ad2, nf, N);
    k_trust<<<(N + 255) / 256, 256, 0, stream>>>(sf, Wt, bt, trust, ns, N);
    k_gate<<<(E + EPB - 1) / EPB, 256, 0, stream>>>(adj_s, adj_d, sf, x2h, ns, nf, trust,
                                                    We1, be1, We2, be2, betas, glog, E);
    k_layer2<<<N, 128, 0, stream>>>(rowp, adj_s, x2h, as2, ad2, glog, bias2, (float*)d_out);
}

// Round 11
// 311.482 us; speedup vs baseline: 1.8577x; 1.0164x over previous
//
#include <hip/hip_runtime.h>
#include <hip/hip_bf16.h>
#include <hip/hip_fp16.h>

// Problem constants (verified against setup_inputs)
#define C_DIN 128
#define C_H 4
#define C_CH 64     // per-head channels (CHID == COUT == 64)
#define C_HC 256    // H * CH
#define C_S 32
#define ACH 32      // aggregation / fusion chunk (edges)
#define MBLK 64     // GEMM M-tile (rows per block)
#define XROW 264    // LDS row stride in halves (256 + pad, 16B-aligned)

typedef __attribute__((ext_vector_type(8))) _Float16 half8;
typedef __attribute__((ext_vector_type(4))) float f32x4;

__device__ __forceinline__ float lrelu(float x) { return x >= 0.f ? x : 0.2f * x; }

// reductions confined to 32-lane subgroup (offsets <=16 never cross halves)
__device__ __forceinline__ float sub_sum32(float v) {
#pragma unroll
    for (int off = 16; off > 0; off >>= 1) v += __shfl_xor(v, off);
    return v;
}

// ---------------- CSR build ----------------
__global__ void k_count(const int* __restrict__ dst, int* __restrict__ deg, int E) {
    int e = blockIdx.x * blockDim.x + threadIdx.x;
    if (e < E) atomicAdd(&deg[dst[e]], 1);
}

__global__ void k_scan(const int* __restrict__ deg, int* __restrict__ row_ptr,
                       int* __restrict__ cursor, int n) {
    __shared__ int part[1024];
    int t = threadIdx.x;
    const int C = (n + 1023) / 1024;
    int base = t * C;
    int s = 0;
    for (int k = 0; k < C; ++k) {
        int idx = base + k;
        if (idx < n) s += deg[idx];
    }
    part[t] = s;
    __syncthreads();
    for (int off = 1; off < 1024; off <<= 1) {
        int v = (t >= off) ? part[t - off] : 0;
        __syncthreads();
        part[t] += v;
        __syncthreads();
    }
    int run = (t == 0) ? 0 : part[t - 1];
    for (int k = 0; k < C; ++k) {
        int idx = base + k;
        if (idx < n) { row_ptr[idx] = run; cursor[idx] = run; run += deg[idx]; }
    }
    if (t == 1023) row_ptr[n] = run;
}

__global__ void k_scatter(const int* __restrict__ src, const int* __restrict__ dst,
                          int* __restrict__ cursor, int* __restrict__ adj_src, int E) {
    int e = blockIdx.x * blockDim.x + threadIdx.x;
    if (e < E) {
        int d = dst[e];
        int p = atomicAdd(&cursor[d], 1);
        adj_src[p] = src[e];
    }
}

// ---------------- layer 1 GEMM (MFMA fp16): h = x @ W1^T, fused a_s1/a_d1 ----------------
__global__ __launch_bounds__(256) void k_gemm1(
    const float* __restrict__ x, const float* __restrict__ W1,
    const float* __restrict__ att_s, const float* __restrict__ att_d,
    __half* __restrict__ hh_out, float* __restrict__ a_s, float* __restrict__ a_d, int n) {
    __shared__ __align__(16) _Float16 bs[4 * 16 * 64 * 8];  // 64 KB
    __shared__ __align__(16) _Float16 as_[4 * 4 * 64 * 8];  // 16 KB
    int t = threadIdx.x;
    int r0 = blockIdx.x * MBLK;
    {
        int c = t;
        const float4* wrow = (const float4*)(W1 + (size_t)c * C_DIN);
        int nt = c >> 4, cl = c & 15;
#pragma unroll
        for (int ch = 0; ch < 16; ++ch) {
            float4 f0 = wrow[ch * 2], f1 = wrow[ch * 2 + 1];
            int ks = ch >> 2, lg = ch & 3;
            _Float16* dst = &bs[(((ks * 16 + nt) * 64) + (lg * 16 + cl)) * 8];
            dst[0] = (_Float16)f0.x; dst[1] = (_Float16)f0.y;
            dst[2] = (_Float16)f0.z; dst[3] = (_Float16)f0.w;
            dst[4] = (_Float16)f1.x; dst[5] = (_Float16)f1.y;
            dst[6] = (_Float16)f1.z; dst[7] = (_Float16)f1.w;
        }
    }
    {
        int row = t >> 2, q = t & 3;
        int rr = r0 + row;
        int mt = row >> 4, rl = row & 15;
        const float4* xrow = (const float4*)(x + (size_t)rr * C_DIN);
#pragma unroll
        for (int cc = 0; cc < 4; ++cc) {
            int ch = q * 4 + cc;
            float4 f0 = make_float4(0, 0, 0, 0), f1 = make_float4(0, 0, 0, 0);
            if (rr < n) { f0 = xrow[ch * 2]; f1 = xrow[ch * 2 + 1]; }
            int ks = ch >> 2, lg = ch & 3;
            _Float16* dst = &as_[(((ks * 4 + mt) * 64) + (lg * 16 + rl)) * 8];
            dst[0] = (_Float16)f0.x; dst[1] = (_Float16)f0.y;
            dst[2] = (_Float16)f0.z; dst[3] = (_Float16)f0.w;
            dst[4] = (_Float16)f1.x; dst[5] = (_Float16)f1.y;
            dst[6] = (_Float16)f1.z; dst[7] = (_Float16)f1.w;
        }
    }
    __syncthreads();
    int w = t >> 6, l = t & 63;
    f32x4 acc[4][4];
#pragma unroll
    for (int mt = 0; mt < 4; ++mt)
#pragma unroll
        for (int nt = 0; nt < 4; ++nt) acc[mt][nt] = (f32x4){0.f, 0.f, 0.f, 0.f};
#pragma unroll
    for (int ks = 0; ks < 4; ++ks) {
        half8 af[4], bf[4];
#pragma unroll
        for (int mt = 0; mt < 4; ++mt)
            af[mt] = *(const half8*)&as_[(((ks * 4 + mt) * 64) + l) * 8];
#pragma unroll
        for (int nt = 0; nt < 4; ++nt)
            bf[nt] = *(const half8*)&bs[(((ks * 16 + (w * 4 + nt)) * 64) + l) * 8];
#pragma unroll
        for (int mt = 0; mt < 4; ++mt)
#pragma unroll
            for (int nt = 0; nt < 4; ++nt)
                acc[mt][nt] = __builtin_amdgcn_mfma_f32_16x16x32_f16(af[mt], bf[nt],
                                                                     acc[mt][nt], 0, 0, 0);
    }
    int cl = l & 15, rg = l >> 4;
    float atv_s[4], atv_d[4];
#pragma unroll
    for (int nt = 0; nt < 4; ++nt) {
        atv_s[nt] = att_s[w * 64 + nt * 16 + cl];
        atv_d[nt] = att_d[w * 64 + nt * 16 + cl];
    }
#pragma unroll
    for (int mt = 0; mt < 4; ++mt) {
#pragma unroll
        for (int r = 0; r < 4; ++r) {
            int rr = r0 + mt * 16 + rg * 4 + r;
            float vs = 0.f, vd = 0.f;
#pragma unroll
            for (int nt = 0; nt < 4; ++nt) {
                float v = acc[mt][nt][r];
                vs += atv_s[nt] * v;
                vd += atv_d[nt] * v;
                if (rr < n)
                    hh_out[(size_t)rr * C_HC + w * 64 + nt * 16 + cl] = __float2half(v);
            }
#pragma unroll
            for (int off = 1; off < 16; off <<= 1) {
                vs += __shfl_xor(vs, off);
                vd += __shfl_xor(vd, off);
            }
            if (cl == 0 && rr < n) { a_s[rr * C_H + w] = vs; a_d[rr * C_H + w] = vd; }
        }
    }
}

// ---------------- layer 1 aggregation: single pass, unnormalized exp ----------------
// No max subtraction: logits bounded (~|8|), softmax shift-invariant, exp in fp32 safe.
__global__ void k_layer1(const int* __restrict__ row_ptr, const int* __restrict__ adj_src,
                         const __half* __restrict__ hhlf, const float* __restrict__ a_s,
                         const float* __restrict__ a_d, const float* __restrict__ bias1,
                         float* __restrict__ h1) {
    int d = blockIdx.x;
    int t = threadIdx.x, hh = t >> 5, cp = t & 31;
    int beg = row_ptr[d], end = row_ptr[d + 1];
    float adh = a_d[d * C_H + hh];
    float p_self = expf(lrelu(a_s[d * C_H + hh] + adh));
    __shared__ float alpha_l[C_H][ACH];
    __shared__ int src_l[ACH];
    const __half2* selfrow = (const __half2*)(hhlf + (size_t)d * C_HC + hh * 64);
    float2 sv = __half22float2(selfrow[cp]);
    float accx = p_self * sv.x, accy = p_self * sv.y;
    float s_part = (cp == 0) ? p_self : 0.f;
    for (int cbeg = beg; cbeg < end; cbeg += ACH) {
        int cn = min(end - cbeg, ACH);
        __syncthreads();
        if (cp < cn) {
            int s = adj_src[cbeg + cp];
            if (hh == 0) src_l[cp] = s;
            float p = expf(lrelu(a_s[s * C_H + hh] + adh));
            alpha_l[hh][cp] = p;
            s_part += p;
        }
        __syncthreads();
        for (int i = 0; i < cn; ++i) {
            int s = src_l[i];
            float a = alpha_l[hh][i];
            float2 v = __half22float2(
                *(const __half2*)(hhlf + (size_t)s * C_HC + hh * 64 + cp * 2));
            accx += a * v.x;
            accy += a * v.y;
        }
    }
    float s = sub_sum32(s_part);
    float inv = 1.f / (s + 1e-16f);
    __shared__ float2 red[128];
    red[t] = make_float2(accx * inv, accy * inv);
    __syncthreads();
    if (t < 32) {
        float2 r0 = red[t], r1 = red[t + 32], r2 = red[t + 64], r3 = red[t + 96];
        float2 b = *(const float2*)&bias1[t * 2];
        float vx = (r0.x + r1.x + r2.x + r3.x) * 0.25f + b.x;
        float vy = (r0.y + r1.y + r2.y + r3.y) * 0.25f + b.y;
        *(float2*)&h1[(size_t)d * C_CH + t * 2] =
            make_float2(fmaxf(vx, 0.f), fmaxf(vy, 0.f));
    }
}

// ---------------- batch-norm stats ----------------
__global__ void k_bnstats(const float* __restrict__ h1, float* __restrict__ bn, int n) {
    int t = threadIdx.x;
    int c = t & 63, rg = t >> 6;
    float s = 0.f, s2 = 0.f;
    for (int r = blockIdx.x * 4 + rg; r < n; r += gridDim.x * 4) {
        float v = h1[(size_t)r * C_CH + c];
        s += v;
        s2 += v * v;
    }
    __shared__ float ls[256], ls2[256];
    ls[t] = s; ls2[t] = s2;
    __syncthreads();
    if (t < 64) {
        s = ls[t] + ls[t + 64] + ls[t + 128] + ls[t + 192];
        s2 = ls2[t] + ls2[t + 64] + ls2[t + 128] + ls2[t + 192];
        atomicAdd(&bn[c], s);
        atomicAdd(&bn[64 + c], s2);
    }
}

// ---------------- layer 2 GEMM (MFMA fp16): x2 = BN(h1) @ W2^T, fused as2/ad2/nf ----------
// BN finalize (mu/rstd from raw sums) folded into the staging step.
__global__ __launch_bounds__(256) void k_gemm2(
    const float* __restrict__ h1, const float* __restrict__ W2,
    const float* __restrict__ att_s, const float* __restrict__ att_d,
    const float* __restrict__ bn, __half* __restrict__ x2h,
    float* __restrict__ as2, float* __restrict__ ad2, float* __restrict__ nf, int n) {
    __shared__ __align__(16) _Float16 bs[2 * 16 * 64 * 8];  // 32 KB
    __shared__ __align__(16) _Float16 as_[2 * 4 * 64 * 8];  // 8 KB
    __shared__ float nq[64][4];
    int t = threadIdx.x;
    int r0 = blockIdx.x * MBLK;
    {
        int c = t;
        const float4* wrow = (const float4*)(W2 + (size_t)c * C_CH);
        int nt = c >> 4, cl = c & 15;
#pragma unroll
        for (int ch = 0; ch < 8; ++ch) {
            float4 f0 = wrow[ch * 2], f1 = wrow[ch * 2 + 1];
            int ks = ch >> 2, lg = ch & 3;
            _Float16* dst = &bs[(((ks * 16 + nt) * 64) + (lg * 16 + cl)) * 8];
            dst[0] = (_Float16)f0.x; dst[1] = (_Float16)f0.y;
            dst[2] = (_Float16)f0.z; dst[3] = (_Float16)f0.w;
            dst[4] = (_Float16)f1.x; dst[5] = (_Float16)f1.y;
            dst[6] = (_Float16)f1.z; dst[7] = (_Float16)f1.w;
        }
    }
    {
        int row = t >> 2, q = t & 3;
        int rr = r0 + row;
        int mt = row >> 4, rl = row & 15;
        const float invN = 1.f / (float)n;
        const float4* hrow = (const float4*)(h1 + (size_t)rr * C_CH);
#pragma unroll
        for (int cc = 0; cc < 2; ++cc) {
            int ch = q * 2 + cc;
            float4 f0 = make_float4(0, 0, 0, 0), f1 = make_float4(0, 0, 0, 0);
            if (rr < n) { f0 = hrow[ch * 2]; f1 = hrow[ch * 2 + 1]; }
            float4 s0 = *(const float4*)&bn[ch * 8];
            float4 s1 = *(const float4*)&bn[ch * 8 + 4];
            float4 q0 = *(const float4*)&bn[64 + ch * 8];
            float4 q1 = *(const float4*)&bn[64 + ch * 8 + 4];
            float4 mu0 = make_float4(s0.x * invN, s0.y * invN, s0.z * invN, s0.w * invN);
            float4 mu1 = make_float4(s1.x * invN, s1.y * invN, s1.z * invN, s1.w * invN);
            float4 rs0 = make_float4(rsqrtf(q0.x * invN - mu0.x * mu0.x + 1e-5f),
                                     rsqrtf(q0.y * invN - mu0.y * mu0.y + 1e-5f),
                                     rsqrtf(q0.z * invN - mu0.z * mu0.z + 1e-5f),
                                     rsqrtf(q0.w * invN - mu0.w * mu0.w + 1e-5f));
            float4 rs1 = make_float4(rsqrtf(q1.x * invN - mu1.x * mu1.x + 1e-5f),
                                     rsqrtf(q1.y * invN - mu1.y * mu1.y + 1e-5f),
                                     rsqrtf(q1.z * invN - mu1.z * mu1.z + 1e-5f),
                                     rsqrtf(q1.w * invN - mu1.w * mu1.w + 1e-5f));
            int ks = ch >> 2, lg = ch & 3;
            _Float16* dst = &as_[(((ks * 4 + mt) * 64) + (lg * 16 + rl)) * 8];
            dst[0] = (_Float16)((f0.x - mu0.x) * rs0.x);
            dst[1] = (_Float16)((f0.y - mu0.y) * rs0.y);
            dst[2] = (_Float16)((f0.z - mu0.z) * rs0.z);
            dst[3] = (_Float16)((f0.w - mu0.w) * rs0.w);
            dst[4] = (_Float16)((f1.x - mu1.x) * rs1.x);
            dst[5] = (_Float16)((f1.y - mu1.y) * rs1.y);
            dst[6] = (_Float16)((f1.z - mu1.z) * rs1.z);
            dst[7] = (_Float16)((f1.w - mu1.w) * rs1.w);
        }
    }
    __syncthreads();
    int w = t >> 6, l = t & 63;
    f32x4 acc[4][4];
#pragma unroll
    for (int mt = 0; mt < 4; ++mt)
#pragma unroll
        for (int nt = 0; nt < 4; ++nt) acc[mt][nt] = (f32x4){0.f, 0.f, 0.f, 0.f};
#pragma unroll
    for (int ks = 0; ks < 2; ++ks) {
        half8 af[4], bf[4];
#pragma unroll
        for (int mt = 0; mt < 4; ++mt)
            af[mt] = *(const half8*)&as_[(((ks * 4 + mt) * 64) + l) * 8];
#pragma unroll
        for (int nt = 0; nt < 4; ++nt)
            bf[nt] = *(const half8*)&bs[(((ks * 16 + (w * 4 + nt)) * 64) + l) * 8];
#pragma unroll
        for (int mt = 0; mt < 4; ++mt)
#pragma unroll
            for (int nt = 0; nt < 4; ++nt)
                acc[mt][nt] = __builtin_amdgcn_mfma_f32_16x16x32_f16(af[mt], bf[nt],
                                                                     acc[mt][nt], 0, 0, 0);
    }
    int cl = l & 15, rg = l >> 4;
    float atv_s[4], atv_d[4];
#pragma unroll
    for (int nt = 0; nt < 4; ++nt) {
        atv_s[nt] = att_s[w * 64 + nt * 16 + cl];
        atv_d[nt] = att_d[w * 64 + nt * 16 + cl];
    }
#pragma unroll
    for (int mt = 0; mt < 4; ++mt) {
#pragma unroll
        for (int r = 0; r < 4; ++r) {
            int rr = r0 + mt * 16 + rg * 4 + r;
            float vs = 0.f, vd = 0.f, vq = 0.f;
#pragma unroll
            for (int nt = 0; nt < 4; ++nt) {
                float v = acc[mt][nt][r];
                vs += atv_s[nt] * v;
                vd += atv_d[nt] * v;
                vq += v * v;
                if (rr < n)
                    x2h[(size_t)rr * C_HC + w * 64 + nt * 16 + cl] = __float2half(v);
            }
#pragma unroll
            for (int off = 1; off < 16; off <<= 1) {
                vs += __shfl_xor(vs, off);
                vd += __shfl_xor(vd, off);
                vq += __shfl_xor(vq, off);
            }
            if (cl == 0 && rr < n) {
                as2[rr * C_H + w] = vs;
                ad2[rr * C_H + w] = vd;
                nq[mt * 16 + rg * 4 + r][w] = vq;
            }
        }
    }
    __syncthreads();
    if (t < MBLK) {
        int rr = r0 + t;
        if (rr < n) {
            float qq = nq[t][0] + nq[t][1] + nq[t][2] + nq[t][3];
            nf[rr] = fmaxf(sqrtf(qq), 1e-8f);
        }
    }
}

// ---------------- node trust + struct norms ----------------
__global__ void k_trust(const float* __restrict__ sf, const float* __restrict__ Wt,
                        const float* __restrict__ bt, float* __restrict__ trust,
                        float* __restrict__ ns, int n) {
    int i = blockIdx.x * blockDim.x + threadIdx.x;
    if (i >= n) return;
    const float4* r4 = (const float4*)(sf + (size_t)i * C_S);
    const float4* w4 = (const float4*)Wt;
    float d = 0.f, q = 0.f;
#pragma unroll
    for (int k = 0; k < 8; ++k) {
        float4 a = r4[k], w = w4[k];
        d += a.x * w.x + a.y * w.y + a.z * w.z + a.w * w.w;
        q += a.x * a.x + a.y * a.y + a.z * a.z + a.w * a.w;
    }
    trust[i] = 1.f / (1.f + expf(-(d + bt[0])));
    ns[i] = fmaxf(sqrtf(q), 1e-8f);
}

// ---------------- fused layer 2: gate + softmax + aggregate (flash-style) ----------------
// Block per dst node d, 128 threads. Per 32-edge chunk: stage x2h[j] rows in LDS once,
// compute cosine dots (quad per edge) + gate MLP (thread per edge) + unnormalized-exp
// accumulation all from the same staged rows. Single pass over edges, no glog buffer.
__global__ __launch_bounds__(128) void k_fused2(
    const int* __restrict__ row_ptr, const int* __restrict__ adj_src,
    const float* __restrict__ sf, const __half* __restrict__ x2h,
    const float* __restrict__ ns, const float* __restrict__ nf,
    const float* __restrict__ trust, const float* __restrict__ as2,
    const float* __restrict__ ad2, const float* __restrict__ We1,
    const float* __restrict__ be1, const float* __restrict__ We2,
    const float* __restrict__ be2, const float* __restrict__ betas,
    const float* __restrict__ bias2, float* __restrict__ out) {
    __shared__ __align__(16) _Float16 xrows[ACH * XROW];  // 16.9 KB staged src rows
    __shared__ __align__(16) _Float16 xd[C_HC];           // dst row
    __shared__ float sfd[C_S];
    __shared__ float pbuf[C_H][ACH];
    __shared__ float2 red[128];
    int d = blockIdx.x;
    int t = threadIdx.x, hh = t >> 5, cp = t & 31;
    int beg = row_ptr[d], end = row_ptr[d + 1];
    // prologue: stage dst row + dst struct row
    if (t < 32) {
        ((float4*)xd)[t] = ((const float4*)(x2h + (size_t)d * C_HC))[t];
    } else if (t < 40) {
        ((float4*)sfd)[t - 32] = ((const float4*)(sf + (size_t)d * C_S))[t - 32];
    }
    float4 ad2d = *(const float4*)&ad2[d * C_H];
    float nsd = ns[d], nfd = nf[d], trd = trust[d];
    int er = t >> 2, q = t & 3;     // quad mapping: 4 threads per edge
    float accx = 0.f, accy = 0.f, s_part = 0.f;
    for (int cbeg = beg; cbeg < end; cbeg += ACH) {
        int cn = min(end - cbeg, ACH);
        __syncthreads();  // prev chunk rows/pbuf consumed (also covers prologue, 1st iter)
        int sload = 0;
        if (q == 0 && er < cn) sload = adj_src[cbeg + er];
        int j = __shfl(sload, (t & 63) & ~3);
        // stage src rows: quad thread q writes halves [q*64, q*64+64) of row er
        if (er < cn) {
            const float4* grow = (const float4*)(x2h + (size_t)j * C_HC) + q * 8;
            float4* lrow = (float4*)&xrows[er * XROW + q * 64];
#pragma unroll
            for (int u = 0; u < 8; ++u) lrow[u] = grow[u];
        }
        __syncthreads();  // rows staged
        // cosine dots from LDS (interleaved halves: quad q handles halves {8m+2q,8m+2q+1})
        float fd = 0.f, sd = 0.f;
        if (er < cn) {
            const _Float16* xr = &xrows[er * XROW];
#pragma unroll
            for (int m = 0; m < 32; ++m) {
                float2 a = __half22float2(*(const __half2*)&xr[m * 8 + q * 2]);
                float2 b = __half22float2(*(const __half2*)&xd[m * 8 + q * 2]);
                fd += a.x * b.x + a.y * b.y;
            }
            const float4* sj = (const float4*)(sf + (size_t)j * C_S) + q * 2;
#pragma unroll
            for (int u = 0; u < 2; ++u) {
                float4 a = sj[u];
                float4 b = *(const float4*)&sfd[q * 8 + u * 4];
                sd += a.x * b.x + a.y * b.y + a.z * b.z + a.w * b.w;
            }
        }
        fd += __shfl_xor(fd, 1); fd += __shfl_xor(fd, 2);
        sd += __shfl_xor(sd, 1); sd += __shfl_xor(sd, 2);
        // gate tail: one thread per edge
        if (q == 0 && er < cn) {
            float ss = sd / (nsd * ns[j]);
            float fs = fd / (nfd * nf[j]);
            float agr = ss * fs;
            float con = fabsf(ss - fs);
            float gate = be2[0];
#pragma unroll
            for (int o = 0; o < 8; ++o) {
                float hdn = We1[o * 4 + 0] * ss + We1[o * 4 + 1] * fs +
                            We1[o * 4 + 2] * agr + We1[o * 4 + 3] * con + be1[o];
                gate += We2[o] * fmaxf(hdn, 0.f);
            }
            float eb = (1.f / (1.f + expf(-gate))) * fmaxf(agr, 0.f);
            float et = sqrtf(fmaxf(trd * trust[j], 0.f));
            float tb = et * fmaxf(0.5f * (ss + fs), 0.f);
            float g = betas[0] * ss + betas[1] * fs + betas[2] * agr +
                      betas[3] * eb + betas[4] * tb;
            float4 asj = *(const float4*)&as2[j * C_H];
            pbuf[0][er] = expf(lrelu(asj.x + ad2d.x) + g);
            pbuf[1][er] = expf(lrelu(asj.y + ad2d.y) + g);
            pbuf[2][er] = expf(lrelu(asj.z + ad2d.z) + g);
            pbuf[3][er] = expf(lrelu(asj.w + ad2d.w) + g);
        }
        __syncthreads();  // pbuf ready
        // accumulate from staged rows
        for (int i = 0; i < cn; ++i) {
            float pv = pbuf[hh][i];
            float2 v = __half22float2(
                *(const __half2*)&xrows[i * XROW + hh * 64 + cp * 2]);
            accx += pv * v.x;
            accy += pv * v.y;
        }
        if (cp < cn) s_part += pbuf[hh][cp];
    }
    float s = sub_sum32(s_part);
    float inv = 1.f / (s + 1e-16f);
    red[t] = make_float2(accx * inv, accy * inv);
    __syncthreads();
    if (t < 32) {
        float2 r0 = red[t], r1 = red[t + 32], r2 = red[t + 64], r3 = red[t + 96];
        float2 b = *(const float2*)&bias2[t * 2];
        float vx = (r0.x + r1.x + r2.x + r3.x) * 0.25f + b.x;
        float vy = (r0.y + r1.y + r2.y + r3.y) * 0.25f + b.y;
        *(float2*)&out[(size_t)d * C_CH + t * 2] = make_float2(vx, vy);
    }
}

static inline size_t al256(size_t x) { return (x + 255) & ~(size_t)255; }

extern "C" void kernel_launch(void* const* d_in, const int* in_sizes, int n_in,
                              void* d_out, int out_size, void* d_ws, size_t ws_size,
                              hipStream_t stream) {
    const float* x      = (const float*)d_in[0];
    const int*   ei     = (const int*)d_in[1];
    const float* sf     = (const float*)d_in[2];
    const float* W1     = (const float*)d_in[3];
    const float* atts1  = (const float*)d_in[4];
    const float* attd1  = (const float*)d_in[5];
    const float* bias1  = (const float*)d_in[6];
    const float* W2     = (const float*)d_in[7];
    const float* atts2  = (const float*)d_in[8];
    const float* attd2  = (const float*)d_in[9];
    const float* bias2  = (const float*)d_in[10];
    const float* Wt     = (const float*)d_in[11];
    const float* bt     = (const float*)d_in[12];
    const float* We1    = (const float*)d_in[13];
    const float* be1    = (const float*)d_in[14];
    const float* We2    = (const float*)d_in[15];
    const float* be2    = (const float*)d_in[16];
    const float* betas  = (const float*)d_in[17];

    const int N = in_sizes[0] / C_DIN;
    const int E = in_sizes[1] / 2;
    const int* srcs = ei;
    const int* dsts = ei + E;

    // workspace carve-up; disjoint-lifetime aliases: x2h reuses hhlf,
    // as2/ad2 reuse a_s1/a_d1
    char* p = (char*)d_ws;
    size_t off = 0;
    auto take = [&](size_t bytes) { char* r = p + off; off = al256(off + bytes); return r; };
    __half* hhlf  = (__half*)take((size_t)N * C_HC * 2);  // layer-1 h (fp16); reused as x2h
    float* h1     = (float*)take((size_t)N * C_CH * 4);
    float* a_s1   = (float*)take((size_t)N * C_H * 4);    // reused as as2
    float* a_d1   = (float*)take((size_t)N * C_H * 4);    // reused as ad2
    float* nf     = (float*)take((size_t)N * 4);
    float* ns     = (float*)take((size_t)N * 4);
    float* trust  = (float*)take((size_t)N * 4);
    int*   deg    = (int*)take((size_t)N * 4);
    int*   rowp   = (int*)take((size_t)(N + 1) * 4);
    int*   cursor = (int*)take((size_t)N * 4);
    int*   adj_s  = (int*)take((size_t)E * 4);
    float* bn     = (float*)take(128 * 4);  // [0:64) sum, [64:128) sumsq
    (void)ws_size;
    __half* x2h = hhlf;   // alias: hhlf dead after k_layer1, x2h born in k_gemm2
    float* as2  = a_s1;   // alias: a_s1 dead after k_layer1
    float* ad2  = a_d1;   // alias: a_d1 dead after k_layer1

    hipMemsetAsync(deg, 0, (size_t)N * 4, stream);
    hipMemsetAsync(bn, 0, 128 * 4, stream);

    // CSR build
    k_count<<<(E + 255) / 256, 256, 0, stream>>>(dsts, deg, E);
    k_scan<<<1, 1024, 0, stream>>>(deg, rowp, cursor, N);
    k_scatter<<<(E + 255) / 256, 256, 0, stream>>>(srcs, dsts, cursor, adj_s, E);

    // layer 1
    k_gemm1<<<(N + MBLK - 1) / MBLK, 256, 0, stream>>>(x, W1, atts1, attd1, hhlf, a_s1, a_d1, N);
    k_layer1<<<N, 128, 0, stream>>>(rowp, adj_s, hhlf, a_s1, a_d1, bias1, h1);
    k_bnstats<<<128, 256, 0, stream>>>(h1, bn, N);

    // layer 2
    k_gemm2<<<(N + MBLK - 1) / MBLK, 256, 0, stream>>>(h1, W2, atts2, attd2, bn, x2h,
                                                       as2, ad2, nf, N);
    k_trust<<<(N + 255) / 256, 256, 0, stream>>>(sf, Wt, bt, trust, ns, N);
    k_fused2<<<N, 128, 0, stream>>>(rowp, adj_s, sf, x2h, ns, nf, trust, as2, ad2,
                                    We1, be1, We2, be2, betas, bias2, (float*)d_out);
}